// Round 6
// baseline (287.037 us; speedup 1.0000x reference)
//
#include <hip/hip_runtime.h>
#include <stdint.h>

// Problem constants (Grok1MoE): B=4, S=1024 -> T=4096 tokens
#define T_TOK 4096
#define HDIM  1024
#define NEXP  8
#define IDIM  2048
#define BK    64
#define NASSIGN (T_TOK * 2)

typedef short short8 __attribute__((ext_vector_type(8)));
typedef float f32x4 __attribute__((ext_vector_type(4)));

__device__ __forceinline__ unsigned short f32_to_bf16(float f) {
  union { float f; uint32_t u; } v; v.f = f;
  uint32_t r = 0x7FFFu + ((v.u >> 16) & 1u);   // round-to-nearest-even
  return (unsigned short)((v.u + r) >> 16);
}

__device__ __forceinline__ void gload16(const void* g, void* l) {
  __builtin_amdgcn_global_load_lds(
      (const __attribute__((address_space(1))) uint32_t*)g,
      (__attribute__((address_space(3))) uint32_t*)l, 16, 0, 0);
}

// ---------------------------------------------------------------------------
// cast f32 -> bf16 for the three weight tensors in one launch (grid.y = which)
// ---------------------------------------------------------------------------
__global__ void cast_w3_kernel(const float* __restrict__ w1,
                               const float* __restrict__ w3,
                               const float* __restrict__ w2,
                               unsigned short* __restrict__ w1b,
                               unsigned short* __restrict__ w3b,
                               unsigned short* __restrict__ w2b, int n8) {
  int i = blockIdx.x * blockDim.x + threadIdx.x;
  if (i >= n8) return;
  const float* src; unsigned short* dst;
  if (blockIdx.y == 0)      { src = w1; dst = w1b; }
  else if (blockIdx.y == 1) { src = w3; dst = w3b; }
  else                      { src = w2; dst = w2b; }
  const float4* s = (const float4*)src + (size_t)i * 2;
  float4 a = s[0], b = s[1];
  short8 o;
  o[0] = f32_to_bf16(a.x); o[1] = f32_to_bf16(a.y);
  o[2] = f32_to_bf16(a.z); o[3] = f32_to_bf16(a.w);
  o[4] = f32_to_bf16(b.x); o[5] = f32_to_bf16(b.y);
  o[6] = f32_to_bf16(b.z); o[7] = f32_to_bf16(b.w);
  ((short8*)dst)[i] = o;
}

// ---------------------------------------------------------------------------
// Router core + x-cast. 512 blocks x 256 threads; 8 tokens/block (2/wave).
// NO atomics: writes per-assignment expert id (eids) + gate weight (gate_a).
// ---------------------------------------------------------------------------
__global__ __launch_bounds__(256)
void router_core(const float* __restrict__ x, const float* __restrict__ wg,
                 unsigned short* __restrict__ xb,
                 unsigned char* __restrict__ eids,
                 float* __restrict__ gate_a) {
  __shared__ float wgs[NEXP * HDIM];   // 32 KiB
  const int tid = threadIdx.x;
#pragma unroll
  for (int i = 0; i < NEXP * HDIM / 4 / 256; ++i)
    ((float4*)wgs)[i * 256 + tid] = ((const float4*)wg)[i * 256 + tid];
  __syncthreads();

  const int wv = tid >> 6, lane = tid & 63;
#pragma unroll
  for (int tt = 0; tt < 2; ++tt) {
    const int t = blockIdx.x * 8 + wv * 2 + tt;
    const float* xr = x + (size_t)t * HDIM;
    float acc0 = 0.f, acc1v = 0.f, acc2 = 0.f, acc3 = 0.f;
    float acc4 = 0.f, acc5 = 0.f, acc6 = 0.f, acc7 = 0.f;
#pragma unroll
    for (int it = 0; it < 4; ++it) {
      const int j = it * 256 + lane * 4;
      const float4 xv = *(const float4*)(xr + j);
      ushort4 u;
      u.x = f32_to_bf16(xv.x); u.y = f32_to_bf16(xv.y);
      u.z = f32_to_bf16(xv.z); u.w = f32_to_bf16(xv.w);
      *(ushort4*)(xb + (size_t)t * HDIM + j) = u;
      const float4 g0 = *(const float4*)(wgs + 0 * HDIM + j);
      const float4 g1 = *(const float4*)(wgs + 1 * HDIM + j);
      const float4 g2 = *(const float4*)(wgs + 2 * HDIM + j);
      const float4 g3 = *(const float4*)(wgs + 3 * HDIM + j);
      const float4 g4 = *(const float4*)(wgs + 4 * HDIM + j);
      const float4 g5 = *(const float4*)(wgs + 5 * HDIM + j);
      const float4 g6 = *(const float4*)(wgs + 6 * HDIM + j);
      const float4 g7 = *(const float4*)(wgs + 7 * HDIM + j);
      acc0 += xv.x * g0.x + xv.y * g0.y + xv.z * g0.z + xv.w * g0.w;
      acc1v += xv.x * g1.x + xv.y * g1.y + xv.z * g1.z + xv.w * g1.w;
      acc2 += xv.x * g2.x + xv.y * g2.y + xv.z * g2.z + xv.w * g2.w;
      acc3 += xv.x * g3.x + xv.y * g3.y + xv.z * g3.z + xv.w * g3.w;
      acc4 += xv.x * g4.x + xv.y * g4.y + xv.z * g4.z + xv.w * g4.w;
      acc5 += xv.x * g5.x + xv.y * g5.y + xv.z * g5.z + xv.w * g5.w;
      acc6 += xv.x * g6.x + xv.y * g6.y + xv.z * g6.z + xv.w * g6.w;
      acc7 += xv.x * g7.x + xv.y * g7.y + xv.z * g7.z + xv.w * g7.w;
    }
    float acc[NEXP] = {acc0, acc1v, acc2, acc3, acc4, acc5, acc6, acc7};
#pragma unroll
    for (int e = 0; e < NEXP; ++e) {
#pragma unroll
      for (int off = 32; off > 0; off >>= 1) acc[e] += __shfl_xor(acc[e], off);
    }
    if (lane == 0) {
      float p[NEXP];
      float mx = -1e30f;
#pragma unroll
      for (int e = 0; e < NEXP; ++e) {
        float l = 30.0f * tanhf(acc[e] * (1.0f / 30.0f));
        p[e] = l;
        mx = fmaxf(mx, l);
      }
      float s = 0.f;
#pragma unroll
      for (int e = 0; e < NEXP; ++e) { p[e] = expf(p[e] - mx); s += p[e]; }
      const float inv = 1.0f / s;
#pragma unroll
      for (int e = 0; e < NEXP; ++e) p[e] *= inv;
      int i0 = 0;
#pragma unroll
      for (int e = 1; e < NEXP; ++e) if (p[e] > p[i0]) i0 = e;
      int i1 = (i0 == 0) ? 1 : 0;
#pragma unroll
      for (int e = 0; e < NEXP; ++e) if (e != i1 && e != i0 && p[e] > p[i1]) i1 = e;
      eids[t * 2]     = (unsigned char)i0;
      gate_a[t * 2]   = p[i0];
      eids[t * 2 + 1] = (unsigned char)i1;
      gate_a[t * 2 + 1] = p[i1];
    }
  }
}

// ---------------------------------------------------------------------------
// Build per-expert compacted lists with ballot prefix sums. 8 blocks x 1024.
// ---------------------------------------------------------------------------
__global__ __launch_bounds__(1024)
void build_lists(const unsigned char* __restrict__ eids,
                 int* __restrict__ counts, int* __restrict__ list) {
  const int e = blockIdx.x;
  const int tid = threadIdx.x;
  const int wid = tid >> 6, lane = tid & 63;
  __shared__ int wave_tot[16];
  __shared__ int running;
  if (tid == 0) running = 0;
  __syncthreads();
#pragma unroll
  for (int c = 0; c < NASSIGN; c += 1024) {
    const int slot = c + tid;
    const bool match = ((int)eids[slot] == e);
    const unsigned long long mask = __ballot(match);
    if (lane == 0) wave_tot[wid] = __popcll(mask);
    __syncthreads();
    int base = running;
    for (int w = 0; w < wid; ++w) base += wave_tot[w];
    if (match) {
      const int pre = __popcll(mask & ((1ull << lane) - 1ull));
      list[e * T_TOK + base + pre] = slot;
    }
    __syncthreads();
    if (tid == 0) {
      int tot = 0;
      for (int w = 0; w < 16; ++w) tot += wave_tot[w];
      running += tot;
    }
    __syncthreads();
  }
  if (tid == 0) counts[e] = running;
}

// ---------------------------------------------------------------------------
// PIPELINED GEMM1: act = gelu(Xe@w1[e]^T) * (Xe@w3[e]^T).
// 256x(64+64), 512 threads (8 waves 4m x 2n), BK=64, DOUBLE-BUFFERED LDS,
// counted vmcnt(6) pipeline (issue t+1 before compute t; never drain to 0
// in the main loop), setprio around the MFMA cluster.
// ---------------------------------------------------------------------------
__global__ __launch_bounds__(512, 2)
void moe_gemm1_fast(const unsigned short* __restrict__ xb,
                    const unsigned short* __restrict__ w1b,
                    const unsigned short* __restrict__ w3b,
                    const int* __restrict__ counts, const int* __restrict__ list,
                    unsigned short* __restrict__ act) {
  const int e = blockIdx.z;
  const int cnt = counts[e];
  const int m0 = blockIdx.y * 256;
  if (m0 >= cnt) return;
  const int n0 = blockIdx.x * 64;

  __shared__ __align__(16) unsigned short As[2][256 * BK];   // 2 x 32 KiB
  __shared__ __align__(16) unsigned short B1s[2][64 * BK];   // 2 x 8 KiB
  __shared__ __align__(16) unsigned short B3s[2][64 * BK];   // 2 x 8 KiB
  __shared__ int entry_l[256];

  const int tid = threadIdx.x;
  if (tid < 256) entry_l[tid] = (m0 + tid < cnt) ? list[e * T_TOK + m0 + tid] : -1;
  __syncthreads();

  const int lane = tid & 63;
  const int l15 = lane & 15;
  const int kg  = lane >> 4;
  const int wid = tid >> 6;                       // 0..7
  const int wvu = __builtin_amdgcn_readfirstlane(wid);
  const int wm = wid >> 1, wn = wid & 1;          // 4m x 2n

  const int srow8  = lane >> 3;
  const int schunk = (lane & 7) ^ srow8;          // inverse-swizzled source chunk

  const unsigned short* aSrc[4];
#pragma unroll
  for (int r = 0; r < 4; ++r) {
    const int row = r * 64 + wid * 8 + srow8;
    const int en = entry_l[row];
    const int tok = (en >= 0) ? (en >> 1) : 0;
    aSrc[r] = xb + (size_t)tok * HDIM + schunk * 8;
  }
  const unsigned short* b1Src = w1b + ((size_t)e * IDIM + n0 + wid * 8 + srow8) * HDIM + schunk * 8;
  const unsigned short* b3Src = w3b + ((size_t)e * IDIM + n0 + wid * 8 + srow8) * HDIM + schunk * 8;

  int aOff[4][2], bOff[2][2];
#pragma unroll
  for (int mf = 0; mf < 4; ++mf)
#pragma unroll
    for (int ks = 0; ks < 2; ++ks) {
      const int row = wm * 64 + mf * 16 + l15;
      aOff[mf][ks] = row * 128 + (((ks * 4 + kg) ^ (row & 7)) * 16);
    }
#pragma unroll
  for (int nf = 0; nf < 2; ++nf)
#pragma unroll
    for (int ks = 0; ks < 2; ++ks) {
      const int row = wn * 32 + nf * 16 + l15;
      bOff[nf][ks] = row * 128 + (((ks * 4 + kg) ^ (row & 7)) * 16);
    }

  f32x4 acc1[4][2], acc3[4][2];
#pragma unroll
  for (int mf = 0; mf < 4; ++mf)
#pragma unroll
    for (int nf = 0; nf < 2; ++nf) {
      acc1[mf][nf] = (f32x4){0.f, 0.f, 0.f, 0.f};
      acc3[mf][nf] = (f32x4){0.f, 0.f, 0.f, 0.f};
    }

#define STAGE1(b)                                                         \
  {                                                                       \
    _Pragma("unroll")                                                     \
    for (int r = 0; r < 4; ++r)                                           \
      gload16(aSrc[r], &As[b][0] + r * 4096 + wvu * 512);                 \
    gload16(b1Src, &B1s[b][0] + wvu * 512);                               \
    gload16(b3Src, &B3s[b][0] + wvu * 512);                               \
    _Pragma("unroll")                                                     \
    for (int r = 0; r < 4; ++r) aSrc[r] += BK;                            \
    b1Src += BK; b3Src += BK;                                             \
  }

#define FRAGS1(cur)                                                       \
  const char* AsB = (const char*)&As[cur][0];                             \
  const char* B1B = (const char*)&B1s[cur][0];                            \
  const char* B3B = (const char*)&B3s[cur][0];                            \
  short8 af[4][2], b1f[2][2], b3f[2][2];                                  \
  _Pragma("unroll")                                                       \
  for (int mf = 0; mf < 4; ++mf)                                          \
    _Pragma("unroll")                                                     \
    for (int ks = 0; ks < 2; ++ks)                                        \
      af[mf][ks] = *(const short8*)(AsB + aOff[mf][ks]);                  \
  _Pragma("unroll")                                                       \
  for (int nf = 0; nf < 2; ++nf)                                          \
    _Pragma("unroll")                                                     \
    for (int ks = 0; ks < 2; ++ks) {                                      \
      b1f[nf][ks] = *(const short8*)(B1B + bOff[nf][ks]);                 \
      b3f[nf][ks] = *(const short8*)(B3B + bOff[nf][ks]);                 \
    }

#define MFMA1                                                             \
  _Pragma("unroll")                                                       \
  for (int mf = 0; mf < 4; ++mf)                                          \
    _Pragma("unroll")                                                     \
    for (int nf = 0; nf < 2; ++nf)                                        \
      _Pragma("unroll")                                                   \
      for (int ks = 0; ks < 2; ++ks) {                                    \
        acc1[mf][nf] = __builtin_amdgcn_mfma_f32_16x16x32_bf16(           \
            af[mf][ks], b1f[nf][ks], acc1[mf][nf], 0, 0, 0);              \
        acc3[mf][nf] = __builtin_amdgcn_mfma_f32_16x16x32_bf16(           \
            af[mf][ks], b3f[nf][ks], acc3[mf][nf], 0, 0, 0);              \
      }

  STAGE1(0);                         // prologue: tile 0 in flight
#pragma unroll
  for (int t = 0; t < (HDIM / BK) - 1; ++t) {
    const int cur = t & 1;
    STAGE1(cur ^ 1);                 // issue tile t+1 (6 loads stay in flight)
    asm volatile("s_waitcnt vmcnt(6)" ::: "memory");   // tile t's loads landed
    __builtin_amdgcn_sched_barrier(0);
    __builtin_amdgcn_s_barrier();    // buf[cur] staged by all waves
    __builtin_amdgcn_sched_barrier(0);
    {
      FRAGS1(cur)
      asm volatile("s_waitcnt lgkmcnt(0)" ::: "memory");
      __builtin_amdgcn_sched_barrier(0);
      __builtin_amdgcn_s_barrier();  // all reads of buf[cur] retired
      __builtin_amdgcn_s_setprio(1);
      MFMA1
      __builtin_amdgcn_s_setprio(0);
    }
  }
  {                                  // peeled last tile: drain fully
    const int cur = ((HDIM / BK) - 1) & 1;
    asm volatile("s_waitcnt vmcnt(0)" ::: "memory");
    __builtin_amdgcn_sched_barrier(0);
    __builtin_amdgcn_s_barrier();
    __builtin_amdgcn_sched_barrier(0);
    {
      FRAGS1(cur)
      asm volatile("s_waitcnt lgkmcnt(0)" ::: "memory");
      __builtin_amdgcn_sched_barrier(0);
      MFMA1
    }
  }
#undef STAGE1
#undef FRAGS1
#undef MFMA1

  // epilogue: act = gelu_exact(h1) * h3 -> bf16
#pragma unroll
  for (int mf = 0; mf < 4; ++mf) {
#pragma unroll
    for (int i = 0; i < 4; ++i) {
      const int r = wm * 64 + mf * 16 + kg * 4 + i;  // C/D: row=(lane>>4)*4+i
      const int en = entry_l[r];
      if (en < 0) continue;
      unsigned short* arow = act + (size_t)en * IDIM + n0 + wn * 32;
#pragma unroll
      for (int nf = 0; nf < 2; ++nf) {
        const float h1 = acc1[mf][nf][i];
        const float h3 = acc3[mf][nf][i];
        const float g = 0.5f * h1 * (1.0f + erff(h1 * 0.70710678118f));
        arow[nf * 16 + l15] = f32_to_bf16(g * h3);  // C/D: col=lane&15
      }
    }
  }
}

// ---------------------------------------------------------------------------
// PIPELINED GEMM2: ybuf[en] = gate * (act[en] @ w2[e]^T). NO atomics.
// 256x128, 512 threads (8 waves 4m x 2n), BK=64, double-buffered, vmcnt(6).
// ---------------------------------------------------------------------------
__global__ __launch_bounds__(512, 2)
void moe_gemm2_fast(const unsigned short* __restrict__ act,
                    const unsigned short* __restrict__ w2b,
                    const int* __restrict__ counts, const int* __restrict__ list,
                    const float* __restrict__ gate_a,
                    float* __restrict__ ybuf) {
  const int e = blockIdx.z;
  const int cnt = counts[e];
  const int m0 = blockIdx.y * 256;
  if (m0 >= cnt) return;
  const int n0 = blockIdx.x * 128;

  __shared__ __align__(16) unsigned short As[2][256 * BK];   // 2 x 32 KiB
  __shared__ __align__(16) unsigned short Bs[2][128 * BK];   // 2 x 16 KiB
  __shared__ int entry_l[256];

  const int tid = threadIdx.x;
  if (tid < 256) entry_l[tid] = (m0 + tid < cnt) ? list[e * T_TOK + m0 + tid] : -1;
  __syncthreads();

  const int lane = tid & 63;
  const int l15 = lane & 15;
  const int kg  = lane >> 4;
  const int wid = tid >> 6;
  const int wvu = __builtin_amdgcn_readfirstlane(wid);
  const int wm = wid >> 1, wn = wid & 1;

  const int srow8  = lane >> 3;
  const int schunk = (lane & 7) ^ srow8;

  const unsigned short* aSrc[4];
#pragma unroll
  for (int r = 0; r < 4; ++r) {
    const int row = r * 64 + wid * 8 + srow8;
    const int en = entry_l[row];
    const int arow = (en >= 0) ? en : 0;
    aSrc[r] = act + (size_t)arow * IDIM + schunk * 8;
  }
  const unsigned short* bSrc[2];
#pragma unroll
  for (int r = 0; r < 2; ++r) {
    const int row = r * 64 + wid * 8 + srow8;
    bSrc[r] = w2b + ((size_t)e * HDIM + n0 + row) * IDIM + schunk * 8;
  }

  int aOff[4][2], bOff[4][2];
#pragma unroll
  for (int mf = 0; mf < 4; ++mf)
#pragma unroll
    for (int ks = 0; ks < 2; ++ks) {
      const int row = wm * 64 + mf * 16 + l15;
      aOff[mf][ks] = row * 128 + (((ks * 4 + kg) ^ (row & 7)) * 16);
    }
#pragma unroll
  for (int nf = 0; nf < 4; ++nf)
#pragma unroll
    for (int ks = 0; ks < 2; ++ks) {
      const int row = wn * 64 + nf * 16 + l15;
      bOff[nf][ks] = row * 128 + (((ks * 4 + kg) ^ (row & 7)) * 16);
    }

  f32x4 acc[4][4];
#pragma unroll
  for (int mf = 0; mf < 4; ++mf)
#pragma unroll
    for (int nf = 0; nf < 4; ++nf) acc[mf][nf] = (f32x4){0.f, 0.f, 0.f, 0.f};

#define STAGE2(b)                                                         \
  {                                                                       \
    _Pragma("unroll")                                                     \
    for (int r = 0; r < 4; ++r)                                           \
      gload16(aSrc[r], &As[b][0] + r * 4096 + wvu * 512);                 \
    _Pragma("unroll")                                                     \
    for (int r = 0; r < 2; ++r)                                           \
      gload16(bSrc[r], &Bs[b][0] + r * 4096 + wvu * 512);                 \
    _Pragma("unroll")                                                     \
    for (int r = 0; r < 4; ++r) aSrc[r] += BK;                            \
    _Pragma("unroll")                                                     \
    for (int r = 0; r < 2; ++r) bSrc[r] += BK;                            \
  }

#define FRAGS2(cur)                                                       \
  const char* AsB = (const char*)&As[cur][0];                             \
  const char* BsB = (const char*)&Bs[cur][0];                             \
  short8 af[4][2], bf[4][2];                                              \
  _Pragma("unroll")                                                       \
  for (int mf = 0; mf < 4; ++mf)                                          \
    _Pragma("unroll")                                                     \
    for (int ks = 0; ks < 2; ++ks)                                        \
      af[mf][ks] = *(const short8*)(AsB + aOff[mf][ks]);                  \
  _Pragma("unroll")                                                       \
  for (int nf = 0; nf < 4; ++nf)                                          \
    _Pragma("unroll")                                                     \
    for (int ks = 0; ks < 2; ++ks)                                        \
      bf[nf][ks] = *(const short8*)(BsB + bOff[nf][ks]);

#define MFMA2                                                             \
  _Pragma("unroll")                                                       \
  for (int mf = 0; mf < 4; ++mf)                                          \
    _Pragma("unroll")                                                     \
    for (int nf = 0; nf < 4; ++nf)                                        \
      _Pragma("unroll")                                                   \
      for (int ks = 0; ks < 2; ++ks)                                      \
        acc[mf][nf] = __builtin_amdgcn_mfma_f32_16x16x32_bf16(            \
            af[mf][ks], bf[nf][ks], acc[mf][nf], 0, 0, 0);

  STAGE2(0);
#pragma unroll
  for (int t = 0; t < (IDIM / BK) - 1; ++t) {
    const int cur = t & 1;
    STAGE2(cur ^ 1);
    asm volatile("s_waitcnt vmcnt(6)" ::: "memory");
    __builtin_amdgcn_sched_barrier(0);
    __builtin_amdgcn_s_barrier();
    __builtin_amdgcn_sched_barrier(0);
    {
      FRAGS2(cur)
      asm volatile("s_waitcnt lgkmcnt(0)" ::: "memory");
      __builtin_amdgcn_sched_barrier(0);
      __builtin_amdgcn_s_barrier();
      __builtin_amdgcn_s_setprio(1);
      MFMA2
      __builtin_amdgcn_s_setprio(0);
    }
  }
  {
    const int cur = ((IDIM / BK) - 1) & 1;
    asm volatile("s_waitcnt vmcnt(0)" ::: "memory");
    __builtin_amdgcn_sched_barrier(0);
    __builtin_amdgcn_s_barrier();
    __builtin_amdgcn_sched_barrier(0);
    {
      FRAGS2(cur)
      asm volatile("s_waitcnt lgkmcnt(0)" ::: "memory");
      __builtin_amdgcn_sched_barrier(0);
      MFMA2
    }
  }
#undef STAGE2
#undef FRAGS2
#undef MFMA2

#pragma unroll
  for (int mf = 0; mf < 4; ++mf) {
#pragma unroll
    for (int i = 0; i < 4; ++i) {
      const int r = wm * 64 + mf * 16 + kg * 4 + i;
      const int en = entry_l[r];
      if (en < 0) continue;
      const float gate = gate_a[en];
      float* yrow = ybuf + (size_t)en * HDIM + n0 + wn * 64;
#pragma unroll
      for (int nf = 0; nf < 4; ++nf)
        yrow[nf * 16 + l15] = acc[mf][nf][i] * gate;
    }
  }
}

// ---------------------------------------------------------------------------
// combine: out[t] = ybuf[2t] + ybuf[2t+1]
// ---------------------------------------------------------------------------
__global__ __launch_bounds__(256)
void combine_kernel(const float* __restrict__ ybuf, float* __restrict__ out) {
  const int i = blockIdx.x * 256 + threadIdx.x;
  const int t  = i >> 8;
  const int j4 = i & 255;
  const float4 a = ((const float4*)(ybuf + (size_t)(2 * t) * HDIM))[j4];
  const float4 b = ((const float4*)(ybuf + (size_t)(2 * t + 1) * HDIM))[j4];
  float4 o;
  o.x = a.x + b.x; o.y = a.y + b.y; o.z = a.z + b.z; o.w = a.w + b.w;
  ((float4*)out)[i] = o;
}

// ---------------------------------------------------------------------------
// FALLBACK path — used only if ws_size can't hold bf16 weight copies.
// ---------------------------------------------------------------------------
#define LSTRIDE 40

__global__ __launch_bounds__(256, 2)
void moe_gemm1_fb(const unsigned short* __restrict__ xb,
                  const float* __restrict__ w1, const float* __restrict__ w3,
                  const int* __restrict__ counts, const int* __restrict__ list,
                  unsigned short* __restrict__ act) {
  const int e = blockIdx.z;
  const int cnt = counts[e];
  const int m0 = blockIdx.y * 128;
  if (m0 >= cnt) return;
  const int n0 = blockIdx.x * 64;

  __shared__ short As[128 * LSTRIDE];
  __shared__ short B1s[64 * LSTRIDE];
  __shared__ short B3s[64 * LSTRIDE];
  __shared__ int entry_l[128];

  const int tid = threadIdx.x;
  if (tid < 128) entry_l[tid] = (m0 + tid < cnt) ? list[e * T_TOK + m0 + tid] : -1;
  __syncthreads();

  const int lane = tid & 63;
  const int l15 = lane & 15;
  const int kg = lane >> 4;
  const int wv = tid >> 6;
  const int wm = wv >> 1, wn = wv & 1;

  f32x4 acc1[4][2], acc3[4][2];
#pragma unroll
  for (int mf = 0; mf < 4; ++mf)
#pragma unroll
    for (int nf = 0; nf < 2; ++nf) {
      acc1[mf][nf] = (f32x4){0.f, 0.f, 0.f, 0.f};
      acc3[mf][nf] = (f32x4){0.f, 0.f, 0.f, 0.f};
    }

  const int srow = tid >> 2;
  const int scol = (tid & 3) << 3;

  const float* w1base = w1 + ((size_t)e * IDIM + n0) * HDIM;
  const float* w3base = w3 + ((size_t)e * IDIM + n0) * HDIM;

  for (int k0 = 0; k0 < HDIM; k0 += 32) {
#pragma unroll
    for (int it = 0; it < 2; ++it) {
      const int r = srow + it * 64;
      const int en = entry_l[r];
      uint4 v = {0u, 0u, 0u, 0u};
      if (en >= 0)
        v = *(const uint4*)(xb + ((size_t)(en >> 1) * HDIM + k0 + scol));
      *(uint4*)(&As[r * LSTRIDE + scol]) = v;
    }
    {
      const float* p1 = w1base + (size_t)srow * HDIM + k0 + scol;
      float4 a0 = *(const float4*)(p1);
      float4 a1 = *(const float4*)(p1 + 4);
      short8 sb;
      sb[0] = f32_to_bf16(a0.x); sb[1] = f32_to_bf16(a0.y);
      sb[2] = f32_to_bf16(a0.z); sb[3] = f32_to_bf16(a0.w);
      sb[4] = f32_to_bf16(a1.x); sb[5] = f32_to_bf16(a1.y);
      sb[6] = f32_to_bf16(a1.z); sb[7] = f32_to_bf16(a1.w);
      *(short8*)(&B1s[srow * LSTRIDE + scol]) = sb;
      const float* p3 = w3base + (size_t)srow * HDIM + k0 + scol;
      float4 c0 = *(const float4*)(p3);
      float4 c1 = *(const float4*)(p3 + 4);
      sb[0] = f32_to_bf16(c0.x); sb[1] = f32_to_bf16(c0.y);
      sb[2] = f32_to_bf16(c0.z); sb[3] = f32_to_bf16(c0.w);
      sb[4] = f32_to_bf16(c1.x); sb[5] = f32_to_bf16(c1.y);
      sb[6] = f32_to_bf16(c1.z); sb[7] = f32_to_bf16(c1.w);
      *(short8*)(&B3s[srow * LSTRIDE + scol]) = sb;
    }
    __syncthreads();
    short8 af[4], b1f[2], b3f[2];
#pragma unroll
    for (int mf = 0; mf < 4; ++mf)
      af[mf] = *(const short8*)(&As[(wm * 64 + mf * 16 + l15) * LSTRIDE + kg * 8]);
#pragma unroll
    for (int nf = 0; nf < 2; ++nf) {
      b1f[nf] = *(const short8*)(&B1s[(wn * 32 + nf * 16 + l15) * LSTRIDE + kg * 8]);
      b3f[nf] = *(const short8*)(&B3s[(wn * 32 + nf * 16 + l15) * LSTRIDE + kg * 8]);
    }
#pragma unroll
    for (int mf = 0; mf < 4; ++mf)
#pragma unroll
      for (int nf = 0; nf < 2; ++nf) {
        acc1[mf][nf] = __builtin_amdgcn_mfma_f32_16x16x32_bf16(af[mf], b1f[nf], acc1[mf][nf], 0, 0, 0);
        acc3[mf][nf] = __builtin_amdgcn_mfma_f32_16x16x32_bf16(af[mf], b3f[nf], acc3[mf][nf], 0, 0, 0);
      }
    __syncthreads();
  }

#pragma unroll
  for (int mf = 0; mf < 4; ++mf) {
#pragma unroll
    for (int i = 0; i < 4; ++i) {
      const int r = wm * 64 + mf * 16 + kg * 4 + i;
      const int en = entry_l[r];
      if (en < 0) continue;
      unsigned short* arow = act + (size_t)en * IDIM + n0 + wn * 32;
#pragma unroll
      for (int nf = 0; nf < 2; ++nf) {
        const float h1 = acc1[mf][nf][i];
        const float h3 = acc3[mf][nf][i];
        const float g = 0.5f * h1 * (1.0f + erff(h1 * 0.70710678118f));
        arow[nf * 16 + l15] = f32_to_bf16(g * h3);
      }
    }
  }
}

__global__ __launch_bounds__(256, 2)
void moe_gemm2_fb(const unsigned short* __restrict__ act,
                  const float* __restrict__ w2,
                  const int* __restrict__ counts, const int* __restrict__ list,
                  const float* __restrict__ gate_a,
                  float* __restrict__ out) {
  const int e = blockIdx.z;
  const int cnt = counts[e];
  const int m0 = blockIdx.y * 128;
  if (m0 >= cnt) return;
  const int n0 = blockIdx.x * 64;

  __shared__ short As[128 * LSTRIDE];
  __shared__ short Bs[64 * LSTRIDE];
  __shared__ int entry_l[128];

  const int tid = threadIdx.x;
  if (tid < 128) entry_l[tid] = (m0 + tid < cnt) ? list[e * T_TOK + m0 + tid] : -1;
  __syncthreads();

  const int lane = tid & 63;
  const int l15 = lane & 15;
  const int kg = lane >> 4;
  const int wv = tid >> 6;
  const int wm = wv >> 1, wn = wv & 1;

  f32x4 acc[4][2];
#pragma unroll
  for (int mf = 0; mf < 4; ++mf)
#pragma unroll
    for (int nf = 0; nf < 2; ++nf) acc[mf][nf] = (f32x4){0.f, 0.f, 0.f, 0.f};

  const int srow = tid >> 2;
  const int scol = (tid & 3) << 3;

  const float* w2b2 = w2 + ((size_t)e * HDIM + n0) * IDIM;

  for (int k0 = 0; k0 < IDIM; k0 += 32) {
#pragma unroll
    for (int it = 0; it < 2; ++it) {
      const int r = srow + it * 64;
      const int en = entry_l[r];
      uint4 v = {0u, 0u, 0u, 0u};
      if (en >= 0)
        v = *(const uint4*)(act + ((size_t)en * IDIM + k0 + scol));
      *(uint4*)(&As[r * LSTRIDE + scol]) = v;
    }
    {
      const float* p2 = w2b2 + (size_t)srow * IDIM + k0 + scol;
      float4 a0 = *(const float4*)(p2);
      float4 a1 = *(const float4*)(p2 + 4);
      short8 sb;
      sb[0] = f32_to_bf16(a0.x); sb[1] = f32_to_bf16(a0.y);
      sb[2] = f32_to_bf16(a0.z); sb[3] = f32_to_bf16(a0.w);
      sb[4] = f32_to_bf16(a1.x); sb[5] = f32_to_bf16(a1.y);
      sb[6] = f32_to_bf16(a1.z); sb[7] = f32_to_bf16(a1.w);
      *(short8*)(&Bs[srow * LSTRIDE + scol]) = sb;
    }
    __syncthreads();
    short8 af[4], bf[2];
#pragma unroll
    for (int mf = 0; mf < 4; ++mf)
      af[mf] = *(const short8*)(&As[(wm * 64 + mf * 16 + l15) * LSTRIDE + kg * 8]);
#pragma unroll
    for (int nf = 0; nf < 2; ++nf)
      bf[nf] = *(const short8*)(&Bs[(wn * 32 + nf * 16 + l15) * LSTRIDE + kg * 8]);
#pragma unroll
    for (int mf = 0; mf < 4; ++mf)
#pragma unroll
      for (int nf = 0; nf < 2; ++nf)
        acc[mf][nf] = __builtin_amdgcn_mfma_f32_16x16x32_bf16(af[mf], bf[nf], acc[mf][nf], 0, 0, 0);
    __syncthreads();
  }

#pragma unroll
  for (int mf = 0; mf < 4; ++mf) {
#pragma unroll
    for (int i = 0; i < 4; ++i) {
      const int r = wm * 64 + mf * 16 + kg * 4 + i;
      const int en = entry_l[r];
      if (en < 0) continue;
      const float gate = gate_a[en];
      float* orow = out + (size_t)(en >> 1) * HDIM + n0 + wn * 32;
#pragma unroll
      for (int nf = 0; nf < 2; ++nf)
        atomicAdd(&orow[nf * 16 + l15], acc[mf][nf][i] * gate);
    }
  }
}

// ---------------------------------------------------------------------------
// Launch
// ---------------------------------------------------------------------------
extern "C" void kernel_launch(void* const* d_in, const int* in_sizes, int n_in,
                              void* d_out, int out_size, void* d_ws, size_t ws_size,
                              hipStream_t stream) {
  const float* x  = (const float*)d_in[0];  // [4,1024,1024]
  const float* wg = (const float*)d_in[1];  // [8,1024]
  const float* w1 = (const float*)d_in[2];  // [8,2048,1024]
  const float* w3 = (const float*)d_in[3];  // [8,2048,1024]
  const float* w2 = (const float*)d_in[4];  // [8,1024,2048]
  float* out = (float*)d_out;

  // ws layout
  char* ws = (char*)d_ws;
  int*            counts = (int*)ws;                               // 1 KiB
  int*            list   = (int*)(ws + 1024);                      // 128 KiB
  float*          gate_a = (float*)(ws + 132096);                  // 32 KiB
  unsigned char*  eids   = (unsigned char*)(ws + 165888);          // 8 KiB
  unsigned short* xb     = (unsigned short*)(ws + 262144);         // 8 MiB
  const size_t OFF_ACT = 262144 + (size_t)T_TOK * HDIM * 2;        // 8650752
  unsigned short* act    = (unsigned short*)(ws + OFF_ACT);        // 32 MiB
  const size_t WELEMS = (size_t)NEXP * IDIM * HDIM;                // 16.8M
  const size_t OFF_W1B = OFF_ACT + (size_t)2 * T_TOK * IDIM * 2;   // 42205184
  const size_t OFF_W3B = OFF_W1B + WELEMS * 2;
  const size_t OFF_W2B = OFF_W3B + WELEMS * 2;
  const size_t WS_NEED = OFF_W2B + WELEMS * 2;                     // ~136.3 MiB

  // router core (no atomics) + deterministic list build
  router_core<<<T_TOK / 8, 256, 0, stream>>>(x, wg, xb, eids, gate_a);
  build_lists<<<NEXP, 1024, 0, stream>>>(eids, counts, list);

  if (ws_size >= WS_NEED) {
    unsigned short* w1b = (unsigned short*)(ws + OFF_W1B);
    unsigned short* w3b = (unsigned short*)(ws + OFF_W3B);
    unsigned short* w2b = (unsigned short*)(ws + OFF_W2B);
    // ybuf (32 MiB f32) aliases w1b (33.5 MiB): w1b is dead once gemm1 completes.
    float* ybuf = (float*)(ws + OFF_W1B);
    const int n8 = (int)(WELEMS / 8);
    cast_w3_kernel<<<dim3((n8 + 255) / 256, 3), 256, 0, stream>>>(w1, w3, w2, w1b, w3b, w2b, n8);
    moe_gemm1_fast<<<dim3(IDIM / 64, T_TOK / 256, NEXP), 512, 0, stream>>>(xb, w1b, w3b, counts, list, act);
    moe_gemm2_fast<<<dim3(HDIM / 128, T_TOK / 256, NEXP), 512, 0, stream>>>(act, w2b, counts, list, gate_a, ybuf);
    combine_kernel<<<T_TOK * HDIM / 4 / 256, 256, 0, stream>>>(ybuf, out);
  } else {
    hipMemsetAsync(d_out, 0, (size_t)out_size * sizeof(float), stream);
    moe_gemm1_fb<<<dim3(IDIM / 64, T_TOK / 128, NEXP), 256, 0, stream>>>(xb, w1, w3, counts, list, act);
    moe_gemm2_fb<<<dim3(HDIM / 64, T_TOK / 128, NEXP), 256, 0, stream>>>(act, w2, counts, list, gate_a, out);
  }
}

// Round 7
// 250.715 us; speedup vs baseline: 1.1449x; 1.1449x over previous
//
#include <hip/hip_runtime.h>
#include <stdint.h>

// Problem constants (Grok1MoE): B=4, S=1024 -> T=4096 tokens
#define T_TOK 4096
#define HDIM  1024
#define NEXP  8
#define IDIM  2048
#define BK    64
#define NASSIGN (T_TOK * 2)

typedef short short8 __attribute__((ext_vector_type(8)));
typedef float f32x4 __attribute__((ext_vector_type(4)));

__device__ __forceinline__ unsigned short f32_to_bf16(float f) {
  union { float f; uint32_t u; } v; v.f = f;
  uint32_t r = 0x7FFFu + ((v.u >> 16) & 1u);   // round-to-nearest-even
  return (unsigned short)((v.u + r) >> 16);
}

__device__ __forceinline__ void gload16(const void* g, void* l) {
  __builtin_amdgcn_global_load_lds(
      (const __attribute__((address_space(1))) uint32_t*)g,
      (__attribute__((address_space(3))) uint32_t*)l, 16, 0, 0);
}

// ---------------------------------------------------------------------------
// cast f32 -> bf16 for the three weight tensors in one launch (grid.y = which)
// ---------------------------------------------------------------------------
__global__ void cast_w3_kernel(const float* __restrict__ w1,
                               const float* __restrict__ w3,
                               const float* __restrict__ w2,
                               unsigned short* __restrict__ w1b,
                               unsigned short* __restrict__ w3b,
                               unsigned short* __restrict__ w2b, int n8) {
  int i = blockIdx.x * blockDim.x + threadIdx.x;
  if (i >= n8) return;
  const float* src; unsigned short* dst;
  if (blockIdx.y == 0)      { src = w1; dst = w1b; }
  else if (blockIdx.y == 1) { src = w3; dst = w3b; }
  else                      { src = w2; dst = w2b; }
  const float4* s = (const float4*)src + (size_t)i * 2;
  float4 a = s[0], b = s[1];
  short8 o;
  o[0] = f32_to_bf16(a.x); o[1] = f32_to_bf16(a.y);
  o[2] = f32_to_bf16(a.z); o[3] = f32_to_bf16(a.w);
  o[4] = f32_to_bf16(b.x); o[5] = f32_to_bf16(b.y);
  o[6] = f32_to_bf16(b.z); o[7] = f32_to_bf16(b.w);
  ((short8*)dst)[i] = o;
}

// ---------------------------------------------------------------------------
// Router core + x-cast. 512 blocks x 256 threads; 8 tokens/block (2/wave).
// NO atomics: writes per-assignment expert id (eids) + gate weight (gate_a).
// ---------------------------------------------------------------------------
__global__ __launch_bounds__(256)
void router_core(const float* __restrict__ x, const float* __restrict__ wg,
                 unsigned short* __restrict__ xb,
                 unsigned char* __restrict__ eids,
                 float* __restrict__ gate_a) {
  __shared__ float wgs[NEXP * HDIM];   // 32 KiB
  const int tid = threadIdx.x;
#pragma unroll
  for (int i = 0; i < NEXP * HDIM / 4 / 256; ++i)
    ((float4*)wgs)[i * 256 + tid] = ((const float4*)wg)[i * 256 + tid];
  __syncthreads();

  const int wv = tid >> 6, lane = tid & 63;
#pragma unroll
  for (int tt = 0; tt < 2; ++tt) {
    const int t = blockIdx.x * 8 + wv * 2 + tt;
    const float* xr = x + (size_t)t * HDIM;
    float acc0 = 0.f, acc1v = 0.f, acc2 = 0.f, acc3 = 0.f;
    float acc4 = 0.f, acc5 = 0.f, acc6 = 0.f, acc7 = 0.f;
#pragma unroll
    for (int it = 0; it < 4; ++it) {
      const int j = it * 256 + lane * 4;
      const float4 xv = *(const float4*)(xr + j);
      ushort4 u;
      u.x = f32_to_bf16(xv.x); u.y = f32_to_bf16(xv.y);
      u.z = f32_to_bf16(xv.z); u.w = f32_to_bf16(xv.w);
      *(ushort4*)(xb + (size_t)t * HDIM + j) = u;
      const float4 g0 = *(const float4*)(wgs + 0 * HDIM + j);
      const float4 g1 = *(const float4*)(wgs + 1 * HDIM + j);
      const float4 g2 = *(const float4*)(wgs + 2 * HDIM + j);
      const float4 g3 = *(const float4*)(wgs + 3 * HDIM + j);
      const float4 g4 = *(const float4*)(wgs + 4 * HDIM + j);
      const float4 g5 = *(const float4*)(wgs + 5 * HDIM + j);
      const float4 g6 = *(const float4*)(wgs + 6 * HDIM + j);
      const float4 g7 = *(const float4*)(wgs + 7 * HDIM + j);
      acc0 += xv.x * g0.x + xv.y * g0.y + xv.z * g0.z + xv.w * g0.w;
      acc1v += xv.x * g1.x + xv.y * g1.y + xv.z * g1.z + xv.w * g1.w;
      acc2 += xv.x * g2.x + xv.y * g2.y + xv.z * g2.z + xv.w * g2.w;
      acc3 += xv.x * g3.x + xv.y * g3.y + xv.z * g3.z + xv.w * g3.w;
      acc4 += xv.x * g4.x + xv.y * g4.y + xv.z * g4.z + xv.w * g4.w;
      acc5 += xv.x * g5.x + xv.y * g5.y + xv.z * g5.z + xv.w * g5.w;
      acc6 += xv.x * g6.x + xv.y * g6.y + xv.z * g6.z + xv.w * g6.w;
      acc7 += xv.x * g7.x + xv.y * g7.y + xv.z * g7.z + xv.w * g7.w;
    }
    float acc[NEXP] = {acc0, acc1v, acc2, acc3, acc4, acc5, acc6, acc7};
#pragma unroll
    for (int e = 0; e < NEXP; ++e) {
#pragma unroll
      for (int off = 32; off > 0; off >>= 1) acc[e] += __shfl_xor(acc[e], off);
    }
    if (lane == 0) {
      float p[NEXP];
      float mx = -1e30f;
#pragma unroll
      for (int e = 0; e < NEXP; ++e) {
        float l = 30.0f * tanhf(acc[e] * (1.0f / 30.0f));
        p[e] = l;
        mx = fmaxf(mx, l);
      }
      float s = 0.f;
#pragma unroll
      for (int e = 0; e < NEXP; ++e) { p[e] = expf(p[e] - mx); s += p[e]; }
      const float inv = 1.0f / s;
#pragma unroll
      for (int e = 0; e < NEXP; ++e) p[e] *= inv;
      int i0 = 0;
#pragma unroll
      for (int e = 1; e < NEXP; ++e) if (p[e] > p[i0]) i0 = e;
      int i1 = (i0 == 0) ? 1 : 0;
#pragma unroll
      for (int e = 0; e < NEXP; ++e) if (e != i1 && e != i0 && p[e] > p[i1]) i1 = e;
      eids[t * 2]     = (unsigned char)i0;
      gate_a[t * 2]   = p[i0];
      eids[t * 2 + 1] = (unsigned char)i1;
      gate_a[t * 2 + 1] = p[i1];
    }
  }
}

// ---------------------------------------------------------------------------
// Build per-expert compacted lists with ballot prefix sums. 8 blocks x 1024.
// ---------------------------------------------------------------------------
__global__ __launch_bounds__(1024)
void build_lists(const unsigned char* __restrict__ eids,
                 int* __restrict__ counts, int* __restrict__ list) {
  const int e = blockIdx.x;
  const int tid = threadIdx.x;
  const int wid = tid >> 6, lane = tid & 63;
  __shared__ int wave_tot[16];
  __shared__ int running;
  if (tid == 0) running = 0;
  __syncthreads();
#pragma unroll
  for (int c = 0; c < NASSIGN; c += 1024) {
    const int slot = c + tid;
    const bool match = ((int)eids[slot] == e);
    const unsigned long long mask = __ballot(match);
    if (lane == 0) wave_tot[wid] = __popcll(mask);
    __syncthreads();
    int base = running;
    for (int w = 0; w < wid; ++w) base += wave_tot[w];
    if (match) {
      const int pre = __popcll(mask & ((1ull << lane) - 1ull));
      list[e * T_TOK + base + pre] = slot;
    }
    __syncthreads();
    if (tid == 0) {
      int tot = 0;
      for (int w = 0; w < 16; ++w) tot += wave_tot[w];
      running += tot;
    }
    __syncthreads();
  }
  if (tid == 0) counts[e] = running;
}

// ---------------------------------------------------------------------------
// FAST GEMM1 (r4 winner): act = gelu(Xe@w1[e]^T) * (Xe@w3[e]^T).
// 128x(64+64) tile, 256 threads (4 waves 2m x 2n), BK=64, single-buffer,
// global_load_lds + XOR-chunk swizzle, compiler-scheduled K-loop.
// launch_bounds(256,4): 4 blocks/CU (16 waves) — LDS 33 KB x 4 fits 160 KB.
// ---------------------------------------------------------------------------
__global__ __launch_bounds__(256, 4)
void moe_gemm1_fast(const unsigned short* __restrict__ xb,
                    const unsigned short* __restrict__ w1b,
                    const unsigned short* __restrict__ w3b,
                    const int* __restrict__ counts, const int* __restrict__ list,
                    unsigned short* __restrict__ act) {
  const int e = blockIdx.z;
  const int cnt = counts[e];
  const int m0 = blockIdx.y * 128;
  if (m0 >= cnt) return;
  const int n0 = blockIdx.x * 64;

  __shared__ __align__(16) unsigned short As[128 * BK];   // 16 KiB
  __shared__ __align__(16) unsigned short B1s[64 * BK];   // 8 KiB
  __shared__ __align__(16) unsigned short B3s[64 * BK];   // 8 KiB
  __shared__ int entry_l[128];

  const int tid = threadIdx.x;
  if (tid < 128) entry_l[tid] = (m0 + tid < cnt) ? list[e * T_TOK + m0 + tid] : -1;
  __syncthreads();

  const int lane = tid & 63;
  const int l15 = lane & 15;
  const int kg  = lane >> 4;
  const int wv  = tid >> 6;
  const int wvu = __builtin_amdgcn_readfirstlane(wv);
  const int wm = wv >> 1, wn = wv & 1;

  const int srow8  = lane >> 3;              // row & 7
  const int schunk = (lane & 7) ^ srow8;     // inverse-swizzled source chunk

  const unsigned short* aSrc[4];
#pragma unroll
  for (int r = 0; r < 4; ++r) {
    const int row = r * 32 + wv * 8 + srow8;
    const int en = entry_l[row];
    const int tok = (en >= 0) ? (en >> 1) : 0;
    aSrc[r] = xb + (size_t)tok * HDIM + schunk * 8;
  }
  const unsigned short* b1Src[2];
  const unsigned short* b3Src[2];
#pragma unroll
  for (int r = 0; r < 2; ++r) {
    const int row = r * 32 + wv * 8 + srow8;
    b1Src[r] = w1b + ((size_t)e * IDIM + n0 + row) * HDIM + schunk * 8;
    b3Src[r] = w3b + ((size_t)e * IDIM + n0 + row) * HDIM + schunk * 8;
  }

  // ds_read byte offsets: byte = row*128 + ((ks*4+kg)^(row&7))*16
  int aOff[4][2], bOff[2][2];
#pragma unroll
  for (int mf = 0; mf < 4; ++mf)
#pragma unroll
    for (int ks = 0; ks < 2; ++ks) {
      const int row = wm * 64 + mf * 16 + l15;
      aOff[mf][ks] = row * 128 + (((ks * 4 + kg) ^ (row & 7)) * 16);
    }
#pragma unroll
  for (int nf = 0; nf < 2; ++nf)
#pragma unroll
    for (int ks = 0; ks < 2; ++ks) {
      const int row = wn * 32 + nf * 16 + l15;
      bOff[nf][ks] = row * 128 + (((ks * 4 + kg) ^ (row & 7)) * 16);
    }

  f32x4 acc1[4][2], acc3[4][2];
#pragma unroll
  for (int mf = 0; mf < 4; ++mf)
#pragma unroll
    for (int nf = 0; nf < 2; ++nf) {
      acc1[mf][nf] = (f32x4){0.f, 0.f, 0.f, 0.f};
      acc3[mf][nf] = (f32x4){0.f, 0.f, 0.f, 0.f};
    }

  const char* AsB = (const char*)As;
  const char* B1B = (const char*)B1s;
  const char* B3B = (const char*)B3s;

  for (int k0 = 0; k0 < HDIM; k0 += BK) {
#pragma unroll
    for (int r = 0; r < 4; ++r) gload16(aSrc[r], As + r * 2048 + wvu * 512);
#pragma unroll
    for (int r = 0; r < 2; ++r) {
      gload16(b1Src[r], B1s + r * 2048 + wvu * 512);
      gload16(b3Src[r], B3s + r * 2048 + wvu * 512);
    }
#pragma unroll
    for (int r = 0; r < 4; ++r) aSrc[r] += BK;
#pragma unroll
    for (int r = 0; r < 2; ++r) { b1Src[r] += BK; b3Src[r] += BK; }
    __syncthreads();

    short8 af[4][2], b1f[2][2], b3f[2][2];
#pragma unroll
    for (int mf = 0; mf < 4; ++mf)
#pragma unroll
      for (int ks = 0; ks < 2; ++ks)
        af[mf][ks] = *(const short8*)(AsB + aOff[mf][ks]);
#pragma unroll
    for (int nf = 0; nf < 2; ++nf)
#pragma unroll
      for (int ks = 0; ks < 2; ++ks) {
        b1f[nf][ks] = *(const short8*)(B1B + bOff[nf][ks]);
        b3f[nf][ks] = *(const short8*)(B3B + bOff[nf][ks]);
      }
#pragma unroll
    for (int mf = 0; mf < 4; ++mf)
#pragma unroll
      for (int nf = 0; nf < 2; ++nf)
#pragma unroll
        for (int ks = 0; ks < 2; ++ks) {
          acc1[mf][nf] = __builtin_amdgcn_mfma_f32_16x16x32_bf16(af[mf][ks], b1f[nf][ks], acc1[mf][nf], 0, 0, 0);
          acc3[mf][nf] = __builtin_amdgcn_mfma_f32_16x16x32_bf16(af[mf][ks], b3f[nf][ks], acc3[mf][nf], 0, 0, 0);
        }
    __syncthreads();
  }

  // epilogue: act = gelu_exact(h1) * h3 -> bf16
#pragma unroll
  for (int mf = 0; mf < 4; ++mf) {
#pragma unroll
    for (int i = 0; i < 4; ++i) {
      const int r = wm * 64 + mf * 16 + kg * 4 + i;  // C/D: row=(lane>>4)*4+i
      const int en = entry_l[r];
      if (en < 0) continue;
      unsigned short* arow = act + (size_t)en * IDIM + n0 + wn * 32;
#pragma unroll
      for (int nf = 0; nf < 2; ++nf) {
        const float h1 = acc1[mf][nf][i];
        const float h3 = acc3[mf][nf][i];
        const float g = 0.5f * h1 * (1.0f + erff(h1 * 0.70710678118f));
        arow[nf * 16 + l15] = f32_to_bf16(g * h3);  // C/D: col=lane&15
      }
    }
  }
}

// ---------------------------------------------------------------------------
// FAST GEMM2 (r5 plain): ybuf[en] = gate * (act[en] @ w2[e]^T). NO atomics.
// 256x128 tile, 512 threads (8 waves 4m x 2n), BK=64, single-buffer.
// launch_bounds(512,4): 2 blocks/CU (16 waves) — LDS 48 KB x 2 fits.
// ---------------------------------------------------------------------------
__global__ __launch_bounds__(512, 4)
void moe_gemm2_fast(const unsigned short* __restrict__ act,
                    const unsigned short* __restrict__ w2b,
                    const int* __restrict__ counts, const int* __restrict__ list,
                    const float* __restrict__ gate_a,
                    float* __restrict__ ybuf) {
  const int e = blockIdx.z;
  const int cnt = counts[e];
  const int m0 = blockIdx.y * 256;
  if (m0 >= cnt) return;
  const int n0 = blockIdx.x * 128;

  __shared__ __align__(16) unsigned short As[256 * BK];   // 32 KiB
  __shared__ __align__(16) unsigned short Bs[128 * BK];   // 16 KiB
  __shared__ int entry_l[256];

  const int tid = threadIdx.x;
  if (tid < 256) entry_l[tid] = (m0 + tid < cnt) ? list[e * T_TOK + m0 + tid] : -1;
  __syncthreads();

  const int lane = tid & 63;
  const int l15 = lane & 15;
  const int kg  = lane >> 4;
  const int wid = tid >> 6;
  const int wvu = __builtin_amdgcn_readfirstlane(wid);
  const int wm = wid >> 1, wn = wid & 1;

  const int srow8  = lane >> 3;
  const int schunk = (lane & 7) ^ srow8;

  const unsigned short* aSrc[4];
#pragma unroll
  for (int r = 0; r < 4; ++r) {
    const int row = r * 64 + wid * 8 + srow8;
    const int en = entry_l[row];
    const int arow = (en >= 0) ? en : 0;
    aSrc[r] = act + (size_t)arow * IDIM + schunk * 8;
  }
  const unsigned short* bSrc[2];
#pragma unroll
  for (int r = 0; r < 2; ++r) {
    const int row = r * 64 + wid * 8 + srow8;
    bSrc[r] = w2b + ((size_t)e * HDIM + n0 + row) * IDIM + schunk * 8;
  }

  int aOff[4][2], bOff[4][2];
#pragma unroll
  for (int mf = 0; mf < 4; ++mf)
#pragma unroll
    for (int ks = 0; ks < 2; ++ks) {
      const int row = wm * 64 + mf * 16 + l15;
      aOff[mf][ks] = row * 128 + (((ks * 4 + kg) ^ (row & 7)) * 16);
    }
#pragma unroll
  for (int nf = 0; nf < 4; ++nf)
#pragma unroll
    for (int ks = 0; ks < 2; ++ks) {
      const int row = wn * 64 + nf * 16 + l15;
      bOff[nf][ks] = row * 128 + (((ks * 4 + kg) ^ (row & 7)) * 16);
    }

  f32x4 acc[4][4];
#pragma unroll
  for (int mf = 0; mf < 4; ++mf)
#pragma unroll
    for (int nf = 0; nf < 4; ++nf) acc[mf][nf] = (f32x4){0.f, 0.f, 0.f, 0.f};

  const char* AsB = (const char*)As;
  const char* BsB = (const char*)Bs;

  for (int k0 = 0; k0 < IDIM; k0 += BK) {
#pragma unroll
    for (int r = 0; r < 4; ++r) gload16(aSrc[r], As + r * 4096 + wvu * 512);
#pragma unroll
    for (int r = 0; r < 2; ++r) gload16(bSrc[r], Bs + r * 4096 + wvu * 512);
#pragma unroll
    for (int r = 0; r < 4; ++r) aSrc[r] += BK;
#pragma unroll
    for (int r = 0; r < 2; ++r) bSrc[r] += BK;
    __syncthreads();

    short8 af[4][2], bf[4][2];
#pragma unroll
    for (int mf = 0; mf < 4; ++mf)
#pragma unroll
      for (int ks = 0; ks < 2; ++ks)
        af[mf][ks] = *(const short8*)(AsB + aOff[mf][ks]);
#pragma unroll
    for (int nf = 0; nf < 4; ++nf)
#pragma unroll
      for (int ks = 0; ks < 2; ++ks)
        bf[nf][ks] = *(const short8*)(BsB + bOff[nf][ks]);
#pragma unroll
    for (int mf = 0; mf < 4; ++mf)
#pragma unroll
      for (int nf = 0; nf < 4; ++nf)
#pragma unroll
        for (int ks = 0; ks < 2; ++ks)
          acc[mf][nf] = __builtin_amdgcn_mfma_f32_16x16x32_bf16(af[mf][ks], bf[nf][ks], acc[mf][nf], 0, 0, 0);
    __syncthreads();
  }

#pragma unroll
  for (int mf = 0; mf < 4; ++mf) {
#pragma unroll
    for (int i = 0; i < 4; ++i) {
      const int r = wm * 64 + mf * 16 + kg * 4 + i;
      const int en = entry_l[r];
      if (en < 0) continue;
      const float gate = gate_a[en];
      float* yrow = ybuf + (size_t)en * HDIM + n0 + wn * 64;
#pragma unroll
      for (int nf = 0; nf < 4; ++nf)
        yrow[nf * 16 + l15] = acc[mf][nf][i] * gate;
    }
  }
}

// ---------------------------------------------------------------------------
// combine: out[t] = ybuf[2t] + ybuf[2t+1]
// ---------------------------------------------------------------------------
__global__ __launch_bounds__(256)
void combine_kernel(const float* __restrict__ ybuf, float* __restrict__ out) {
  const int i = blockIdx.x * 256 + threadIdx.x;
  const int t  = i >> 8;
  const int j4 = i & 255;
  const float4 a = ((const float4*)(ybuf + (size_t)(2 * t) * HDIM))[j4];
  const float4 b = ((const float4*)(ybuf + (size_t)(2 * t + 1) * HDIM))[j4];
  float4 o;
  o.x = a.x + b.x; o.y = a.y + b.y; o.z = a.z + b.z; o.w = a.w + b.w;
  ((float4*)out)[i] = o;
}

// ---------------------------------------------------------------------------
// FALLBACK path — used only if ws_size can't hold bf16 weight copies.
// ---------------------------------------------------------------------------
#define LSTRIDE 40

__global__ __launch_bounds__(256, 2)
void moe_gemm1_fb(const unsigned short* __restrict__ xb,
                  const float* __restrict__ w1, const float* __restrict__ w3,
                  const int* __restrict__ counts, const int* __restrict__ list,
                  unsigned short* __restrict__ act) {
  const int e = blockIdx.z;
  const int cnt = counts[e];
  const int m0 = blockIdx.y * 128;
  if (m0 >= cnt) return;
  const int n0 = blockIdx.x * 64;

  __shared__ short As[128 * LSTRIDE];
  __shared__ short B1s[64 * LSTRIDE];
  __shared__ short B3s[64 * LSTRIDE];
  __shared__ int entry_l[128];

  const int tid = threadIdx.x;
  if (tid < 128) entry_l[tid] = (m0 + tid < cnt) ? list[e * T_TOK + m0 + tid] : -1;
  __syncthreads();

  const int lane = tid & 63;
  const int l15 = lane & 15;
  const int kg = lane >> 4;
  const int wv = tid >> 6;
  const int wm = wv >> 1, wn = wv & 1;

  f32x4 acc1[4][2], acc3[4][2];
#pragma unroll
  for (int mf = 0; mf < 4; ++mf)
#pragma unroll
    for (int nf = 0; nf < 2; ++nf) {
      acc1[mf][nf] = (f32x4){0.f, 0.f, 0.f, 0.f};
      acc3[mf][nf] = (f32x4){0.f, 0.f, 0.f, 0.f};
    }

  const int srow = tid >> 2;
  const int scol = (tid & 3) << 3;

  const float* w1base = w1 + ((size_t)e * IDIM + n0) * HDIM;
  const float* w3base = w3 + ((size_t)e * IDIM + n0) * HDIM;

  for (int k0 = 0; k0 < HDIM; k0 += 32) {
#pragma unroll
    for (int it = 0; it < 2; ++it) {
      const int r = srow + it * 64;
      const int en = entry_l[r];
      uint4 v = {0u, 0u, 0u, 0u};
      if (en >= 0)
        v = *(const uint4*)(xb + ((size_t)(en >> 1) * HDIM + k0 + scol));
      *(uint4*)(&As[r * LSTRIDE + scol]) = v;
    }
    {
      const float* p1 = w1base + (size_t)srow * HDIM + k0 + scol;
      float4 a0 = *(const float4*)(p1);
      float4 a1 = *(const float4*)(p1 + 4);
      short8 sb;
      sb[0] = f32_to_bf16(a0.x); sb[1] = f32_to_bf16(a0.y);
      sb[2] = f32_to_bf16(a0.z); sb[3] = f32_to_bf16(a0.w);
      sb[4] = f32_to_bf16(a1.x); sb[5] = f32_to_bf16(a1.y);
      sb[6] = f32_to_bf16(a1.z); sb[7] = f32_to_bf16(a1.w);
      *(short8*)(&B1s[srow * LSTRIDE + scol]) = sb;
      const float* p3 = w3base + (size_t)srow * HDIM + k0 + scol;
      float4 c0 = *(const float4*)(p3);
      float4 c1 = *(const float4*)(p3 + 4);
      sb[0] = f32_to_bf16(c0.x); sb[1] = f32_to_bf16(c0.y);
      sb[2] = f32_to_bf16(c0.z); sb[3] = f32_to_bf16(c0.w);
      sb[4] = f32_to_bf16(c1.x); sb[5] = f32_to_bf16(c1.y);
      sb[6] = f32_to_bf16(c1.z); sb[7] = f32_to_bf16(c1.w);
      *(short8*)(&B3s[srow * LSTRIDE + scol]) = sb;
    }
    __syncthreads();
    short8 af[4], b1f[2], b3f[2];
#pragma unroll
    for (int mf = 0; mf < 4; ++mf)
      af[mf] = *(const short8*)(&As[(wm * 64 + mf * 16 + l15) * LSTRIDE + kg * 8]);
#pragma unroll
    for (int nf = 0; nf < 2; ++nf) {
      b1f[nf] = *(const short8*)(&B1s[(wn * 32 + nf * 16 + l15) * LSTRIDE + kg * 8]);
      b3f[nf] = *(const short8*)(&B3s[(wn * 32 + nf * 16 + l15) * LSTRIDE + kg * 8]);
    }
#pragma unroll
    for (int mf = 0; mf < 4; ++mf)
#pragma unroll
      for (int nf = 0; nf < 2; ++nf) {
        acc1[mf][nf] = __builtin_amdgcn_mfma_f32_16x16x32_bf16(af[mf], b1f[nf], acc1[mf][nf], 0, 0, 0);
        acc3[mf][nf] = __builtin_amdgcn_mfma_f32_16x16x32_bf16(af[mf], b3f[nf], acc3[mf][nf], 0, 0, 0);
      }
    __syncthreads();
  }

#pragma unroll
  for (int mf = 0; mf < 4; ++mf) {
#pragma unroll
    for (int i = 0; i < 4; ++i) {
      const int r = wm * 64 + mf * 16 + kg * 4 + i;
      const int en = entry_l[r];
      if (en < 0) continue;
      unsigned short* arow = act + (size_t)en * IDIM + n0 + wn * 32;
#pragma unroll
      for (int nf = 0; nf < 2; ++nf) {
        const float h1 = acc1[mf][nf][i];
        const float h3 = acc3[mf][nf][i];
        const float g = 0.5f * h1 * (1.0f + erff(h1 * 0.70710678118f));
        arow[nf * 16 + l15] = f32_to_bf16(g * h3);
      }
    }
  }
}

__global__ __launch_bounds__(256, 2)
void moe_gemm2_fb(const unsigned short* __restrict__ act,
                  const float* __restrict__ w2,
                  const int* __restrict__ counts, const int* __restrict__ list,
                  const float* __restrict__ gate_a,
                  float* __restrict__ out) {
  const int e = blockIdx.z;
  const int cnt = counts[e];
  const int m0 = blockIdx.y * 128;
  if (m0 >= cnt) return;
  const int n0 = blockIdx.x * 64;

  __shared__ short As[128 * LSTRIDE];
  __shared__ short Bs[64 * LSTRIDE];
  __shared__ int entry_l[128];

  const int tid = threadIdx.x;
  if (tid < 128) entry_l[tid] = (m0 + tid < cnt) ? list[e * T_TOK + m0 + tid] : -1;
  __syncthreads();

  const int lane = tid & 63;
  const int l15 = lane & 15;
  const int kg = lane >> 4;
  const int wv = tid >> 6;
  const int wm = wv >> 1, wn = wv & 1;

  f32x4 acc[4][2];
#pragma unroll
  for (int mf = 0; mf < 4; ++mf)
#pragma unroll
    for (int nf = 0; nf < 2; ++nf) acc[mf][nf] = (f32x4){0.f, 0.f, 0.f, 0.f};

  const int srow = tid >> 2;
  const int scol = (tid & 3) << 3;

  const float* w2b2 = w2 + ((size_t)e * HDIM + n0) * IDIM;

  for (int k0 = 0; k0 < IDIM; k0 += 32) {
#pragma unroll
    for (int it = 0; it < 2; ++it) {
      const int r = srow + it * 64;
      const int en = entry_l[r];
      uint4 v = {0u, 0u, 0u, 0u};
      if (en >= 0)
        v = *(const uint4*)(act + ((size_t)en * IDIM + k0 + scol));
      *(uint4*)(&As[r * LSTRIDE + scol]) = v;
    }
    {
      const float* p2 = w2b2 + (size_t)srow * IDIM + k0 + scol;
      float4 a0 = *(const float4*)(p2);
      float4 a1 = *(const float4*)(p2 + 4);
      short8 sb;
      sb[0] = f32_to_bf16(a0.x); sb[1] = f32_to_bf16(a0.y);
      sb[2] = f32_to_bf16(a0.z); sb[3] = f32_to_bf16(a0.w);
      sb[4] = f32_to_bf16(a1.x); sb[5] = f32_to_bf16(a1.y);
      sb[6] = f32_to_bf16(a1.z); sb[7] = f32_to_bf16(a1.w);
      *(short8*)(&Bs[srow * LSTRIDE + scol]) = sb;
    }
    __syncthreads();
    short8 af[4], bf[2];
#pragma unroll
    for (int mf = 0; mf < 4; ++mf)
      af[mf] = *(const short8*)(&As[(wm * 64 + mf * 16 + l15) * LSTRIDE + kg * 8]);
#pragma unroll
    for (int nf = 0; nf < 2; ++nf)
      bf[nf] = *(const short8*)(&Bs[(wn * 32 + nf * 16 + l15) * LSTRIDE + kg * 8]);
#pragma unroll
    for (int mf = 0; mf < 4; ++mf)
#pragma unroll
      for (int nf = 0; nf < 2; ++nf)
        acc[mf][nf] = __builtin_amdgcn_mfma_f32_16x16x32_bf16(af[mf], bf[nf], acc[mf][nf], 0, 0, 0);
    __syncthreads();
  }

#pragma unroll
  for (int mf = 0; mf < 4; ++mf) {
#pragma unroll
    for (int i = 0; i < 4; ++i) {
      const int r = wm * 64 + mf * 16 + kg * 4 + i;
      const int en = entry_l[r];
      if (en < 0) continue;
      const float gate = gate_a[en];
      float* orow = out + (size_t)(en >> 1) * HDIM + n0 + wn * 32;
#pragma unroll
      for (int nf = 0; nf < 2; ++nf)
        atomicAdd(&orow[nf * 16 + l15], acc[mf][nf][i] * gate);
    }
  }
}

// ---------------------------------------------------------------------------
// Launch
// ---------------------------------------------------------------------------
extern "C" void kernel_launch(void* const* d_in, const int* in_sizes, int n_in,
                              void* d_out, int out_size, void* d_ws, size_t ws_size,
                              hipStream_t stream) {
  const float* x  = (const float*)d_in[0];  // [4,1024,1024]
  const float* wg = (const float*)d_in[1];  // [8,1024]
  const float* w1 = (const float*)d_in[2];  // [8,2048,1024]
  const float* w3 = (const float*)d_in[3];  // [8,2048,1024]
  const float* w2 = (const float*)d_in[4];  // [8,1024,2048]
  float* out = (float*)d_out;

  // ws layout
  char* ws = (char*)d_ws;
  int*            counts = (int*)ws;                               // 1 KiB
  int*            list   = (int*)(ws + 1024);                      // 128 KiB
  float*          gate_a = (float*)(ws + 132096);                  // 32 KiB
  unsigned char*  eids   = (unsigned char*)(ws + 165888);          // 8 KiB
  unsigned short* xb     = (unsigned short*)(ws + 262144);         // 8 MiB
  const size_t OFF_ACT = 262144 + (size_t)T_TOK * HDIM * 2;        // 8650752
  unsigned short* act    = (unsigned short*)(ws + OFF_ACT);        // 32 MiB
  const size_t WELEMS = (size_t)NEXP * IDIM * HDIM;                // 16.8M
  const size_t OFF_W1B = OFF_ACT + (size_t)2 * T_TOK * IDIM * 2;   // 42205184
  const size_t OFF_W3B = OFF_W1B + WELEMS * 2;
  const size_t OFF_W2B = OFF_W3B + WELEMS * 2;
  const size_t WS_NEED = OFF_W2B + WELEMS * 2;                     // ~136.3 MiB

  // router core (no atomics) + deterministic list build
  router_core<<<T_TOK / 8, 256, 0, stream>>>(x, wg, xb, eids, gate_a);
  build_lists<<<NEXP, 1024, 0, stream>>>(eids, counts, list);

  if (ws_size >= WS_NEED) {
    unsigned short* w1b = (unsigned short*)(ws + OFF_W1B);
    unsigned short* w3b = (unsigned short*)(ws + OFF_W3B);
    unsigned short* w2b = (unsigned short*)(ws + OFF_W2B);
    // ybuf (32 MiB f32) aliases w1b (33.5 MiB): w1b is dead once gemm1 completes.
    float* ybuf = (float*)(ws + OFF_W1B);
    const int n8 = (int)(WELEMS / 8);
    cast_w3_kernel<<<dim3((n8 + 255) / 256, 3), 256, 0, stream>>>(w1, w3, w2, w1b, w3b, w2b, n8);
    moe_gemm1_fast<<<dim3(IDIM / 64, T_TOK / 128, NEXP), 256, 0, stream>>>(xb, w1b, w3b, counts, list, act);
    moe_gemm2_fast<<<dim3(HDIM / 128, T_TOK / 256, NEXP), 512, 0, stream>>>(act, w2b, counts, list, gate_a, ybuf);
    combine_kernel<<<T_TOK * HDIM / 4 / 256, 256, 0, stream>>>(ybuf, out);
  } else {
    hipMemsetAsync(d_out, 0, (size_t)out_size * sizeof(float), stream);
    moe_gemm1_fb<<<dim3(IDIM / 64, T_TOK / 128, NEXP), 256, 0, stream>>>(xb, w1, w3, counts, list, act);
    moe_gemm2_fb<<<dim3(HDIM / 64, T_TOK / 128, NEXP), 256, 0, stream>>>(act, w2, counts, list, gate_a, out);
  }
}

// Round 8
// 227.136 us; speedup vs baseline: 1.2637x; 1.1038x over previous
//
#include <hip/hip_runtime.h>
#include <stdint.h>

// Problem constants (Grok1MoE): B=4, S=1024 -> T=4096 tokens
#define T_TOK 4096
#define HDIM  1024
#define NEXP  8
#define IDIM  2048
#define BK    64
#define NASSIGN (T_TOK * 2)

typedef short short8 __attribute__((ext_vector_type(8)));
typedef float f32x4 __attribute__((ext_vector_type(4)));

__device__ __forceinline__ unsigned short f32_to_bf16(float f) {
  union { float f; uint32_t u; } v; v.f = f;
  uint32_t r = 0x7FFFu + ((v.u >> 16) & 1u);   // round-to-nearest-even
  return (unsigned short)((v.u + r) >> 16);
}

__device__ __forceinline__ void gload16(const void* g, void* l) {
  __builtin_amdgcn_global_load_lds(
      (const __attribute__((address_space(1))) uint32_t*)g,
      (__attribute__((address_space(3))) uint32_t*)l, 16, 0, 0);
}

// ---------------------------------------------------------------------------
// cast f32 -> bf16 for the three weight tensors in one launch (grid.y = which)
// ---------------------------------------------------------------------------
__global__ void cast_w3_kernel(const float* __restrict__ w1,
                               const float* __restrict__ w3,
                               const float* __restrict__ w2,
                               unsigned short* __restrict__ w1b,
                               unsigned short* __restrict__ w3b,
                               unsigned short* __restrict__ w2b, int n8) {
  int i = blockIdx.x * blockDim.x + threadIdx.x;
  if (i >= n8) return;
  const float* src; unsigned short* dst;
  if (blockIdx.y == 0)      { src = w1; dst = w1b; }
  else if (blockIdx.y == 1) { src = w3; dst = w3b; }
  else                      { src = w2; dst = w2b; }
  const float4* s = (const float4*)src + (size_t)i * 2;
  float4 a = s[0], b = s[1];
  short8 o;
  o[0] = f32_to_bf16(a.x); o[1] = f32_to_bf16(a.y);
  o[2] = f32_to_bf16(a.z); o[3] = f32_to_bf16(a.w);
  o[4] = f32_to_bf16(b.x); o[5] = f32_to_bf16(b.y);
  o[6] = f32_to_bf16(b.z); o[7] = f32_to_bf16(b.w);
  ((short8*)dst)[i] = o;
}

// ---------------------------------------------------------------------------
// Router core + x-cast. 512 blocks x 256 threads; 8 tokens/block (2/wave).
// NO atomics: writes per-assignment expert id (eids) + gate weight (gate_a).
// ---------------------------------------------------------------------------
__global__ __launch_bounds__(256)
void router_core(const float* __restrict__ x, const float* __restrict__ wg,
                 unsigned short* __restrict__ xb,
                 unsigned char* __restrict__ eids,
                 float* __restrict__ gate_a) {
  __shared__ float wgs[NEXP * HDIM];   // 32 KiB
  const int tid = threadIdx.x;
#pragma unroll
  for (int i = 0; i < NEXP * HDIM / 4 / 256; ++i)
    ((float4*)wgs)[i * 256 + tid] = ((const float4*)wg)[i * 256 + tid];
  __syncthreads();

  const int wv = tid >> 6, lane = tid & 63;
#pragma unroll
  for (int tt = 0; tt < 2; ++tt) {
    const int t = blockIdx.x * 8 + wv * 2 + tt;
    const float* xr = x + (size_t)t * HDIM;
    float acc0 = 0.f, acc1v = 0.f, acc2 = 0.f, acc3 = 0.f;
    float acc4 = 0.f, acc5 = 0.f, acc6 = 0.f, acc7 = 0.f;
#pragma unroll
    for (int it = 0; it < 4; ++it) {
      const int j = it * 256 + lane * 4;
      const float4 xv = *(const float4*)(xr + j);
      ushort4 u;
      u.x = f32_to_bf16(xv.x); u.y = f32_to_bf16(xv.y);
      u.z = f32_to_bf16(xv.z); u.w = f32_to_bf16(xv.w);
      *(ushort4*)(xb + (size_t)t * HDIM + j) = u;
      const float4 g0 = *(const float4*)(wgs + 0 * HDIM + j);
      const float4 g1 = *(const float4*)(wgs + 1 * HDIM + j);
      const float4 g2 = *(const float4*)(wgs + 2 * HDIM + j);
      const float4 g3 = *(const float4*)(wgs + 3 * HDIM + j);
      const float4 g4 = *(const float4*)(wgs + 4 * HDIM + j);
      const float4 g5 = *(const float4*)(wgs + 5 * HDIM + j);
      const float4 g6 = *(const float4*)(wgs + 6 * HDIM + j);
      const float4 g7 = *(const float4*)(wgs + 7 * HDIM + j);
      acc0 += xv.x * g0.x + xv.y * g0.y + xv.z * g0.z + xv.w * g0.w;
      acc1v += xv.x * g1.x + xv.y * g1.y + xv.z * g1.z + xv.w * g1.w;
      acc2 += xv.x * g2.x + xv.y * g2.y + xv.z * g2.z + xv.w * g2.w;
      acc3 += xv.x * g3.x + xv.y * g3.y + xv.z * g3.z + xv.w * g3.w;
      acc4 += xv.x * g4.x + xv.y * g4.y + xv.z * g4.z + xv.w * g4.w;
      acc5 += xv.x * g5.x + xv.y * g5.y + xv.z * g5.z + xv.w * g5.w;
      acc6 += xv.x * g6.x + xv.y * g6.y + xv.z * g6.z + xv.w * g6.w;
      acc7 += xv.x * g7.x + xv.y * g7.y + xv.z * g7.z + xv.w * g7.w;
    }
    float acc[NEXP] = {acc0, acc1v, acc2, acc3, acc4, acc5, acc6, acc7};
#pragma unroll
    for (int e = 0; e < NEXP; ++e) {
#pragma unroll
      for (int off = 32; off > 0; off >>= 1) acc[e] += __shfl_xor(acc[e], off);
    }
    if (lane == 0) {
      float p[NEXP];
      float mx = -1e30f;
#pragma unroll
      for (int e = 0; e < NEXP; ++e) {
        float l = 30.0f * tanhf(acc[e] * (1.0f / 30.0f));
        p[e] = l;
        mx = fmaxf(mx, l);
      }
      float s = 0.f;
#pragma unroll
      for (int e = 0; e < NEXP; ++e) { p[e] = expf(p[e] - mx); s += p[e]; }
      const float inv = 1.0f / s;
#pragma unroll
      for (int e = 0; e < NEXP; ++e) p[e] *= inv;
      int i0 = 0;
#pragma unroll
      for (int e = 1; e < NEXP; ++e) if (p[e] > p[i0]) i0 = e;
      int i1 = (i0 == 0) ? 1 : 0;
#pragma unroll
      for (int e = 0; e < NEXP; ++e) if (e != i1 && e != i0 && p[e] > p[i1]) i1 = e;
      eids[t * 2]     = (unsigned char)i0;
      gate_a[t * 2]   = p[i0];
      eids[t * 2 + 1] = (unsigned char)i1;
      gate_a[t * 2 + 1] = p[i1];
    }
  }
}

// ---------------------------------------------------------------------------
// Build per-expert compacted lists with ballot prefix sums. 8 blocks x 1024.
// ---------------------------------------------------------------------------
__global__ __launch_bounds__(1024)
void build_lists(const unsigned char* __restrict__ eids,
                 int* __restrict__ counts, int* __restrict__ list) {
  const int e = blockIdx.x;
  const int tid = threadIdx.x;
  const int wid = tid >> 6, lane = tid & 63;
  __shared__ int wave_tot[16];
  __shared__ int running;
  if (tid == 0) running = 0;
  __syncthreads();
#pragma unroll
  for (int c = 0; c < NASSIGN; c += 1024) {
    const int slot = c + tid;
    const bool match = ((int)eids[slot] == e);
    const unsigned long long mask = __ballot(match);
    if (lane == 0) wave_tot[wid] = __popcll(mask);
    __syncthreads();
    int base = running;
    for (int w = 0; w < wid; ++w) base += wave_tot[w];
    if (match) {
      const int pre = __popcll(mask & ((1ull << lane) - 1ull));
      list[e * T_TOK + base + pre] = slot;
    }
    __syncthreads();
    if (tid == 0) {
      int tot = 0;
      for (int w = 0; w < 16; ++w) tot += wave_tot[w];
      running += tot;
    }
    __syncthreads();
  }
  if (tid == 0) counts[e] = running;
}

// ---------------------------------------------------------------------------
// FAST GEMM1 (r4 winner): act = gelu(Xe@w1[e]^T) * (Xe@w3[e]^T).
// 128x(64+64) tile, 256 threads (4 waves 2m x 2n), BK=64, single-buffer,
// global_load_lds + XOR-chunk swizzle, compiler-scheduled K-loop.
// ---------------------------------------------------------------------------
__global__ __launch_bounds__(256, 4)
void moe_gemm1_fast(const unsigned short* __restrict__ xb,
                    const unsigned short* __restrict__ w1b,
                    const unsigned short* __restrict__ w3b,
                    const int* __restrict__ counts, const int* __restrict__ list,
                    unsigned short* __restrict__ act) {
  const int e = blockIdx.z;
  const int cnt = counts[e];
  const int m0 = blockIdx.y * 128;
  if (m0 >= cnt) return;
  const int n0 = blockIdx.x * 64;

  __shared__ __align__(16) unsigned short As[128 * BK];   // 16 KiB
  __shared__ __align__(16) unsigned short B1s[64 * BK];   // 8 KiB
  __shared__ __align__(16) unsigned short B3s[64 * BK];   // 8 KiB
  __shared__ int entry_l[128];

  const int tid = threadIdx.x;
  if (tid < 128) entry_l[tid] = (m0 + tid < cnt) ? list[e * T_TOK + m0 + tid] : -1;
  __syncthreads();

  const int lane = tid & 63;
  const int l15 = lane & 15;
  const int kg  = lane >> 4;
  const int wv  = tid >> 6;
  const int wvu = __builtin_amdgcn_readfirstlane(wv);
  const int wm = wv >> 1, wn = wv & 1;

  const int srow8  = lane >> 3;              // row & 7
  const int schunk = (lane & 7) ^ srow8;     // inverse-swizzled source chunk

  const unsigned short* aSrc[4];
#pragma unroll
  for (int r = 0; r < 4; ++r) {
    const int row = r * 32 + wv * 8 + srow8;
    const int en = entry_l[row];
    const int tok = (en >= 0) ? (en >> 1) : 0;
    aSrc[r] = xb + (size_t)tok * HDIM + schunk * 8;
  }
  const unsigned short* b1Src[2];
  const unsigned short* b3Src[2];
#pragma unroll
  for (int r = 0; r < 2; ++r) {
    const int row = r * 32 + wv * 8 + srow8;
    b1Src[r] = w1b + ((size_t)e * IDIM + n0 + row) * HDIM + schunk * 8;
    b3Src[r] = w3b + ((size_t)e * IDIM + n0 + row) * HDIM + schunk * 8;
  }

  // ds_read byte offsets: byte = row*128 + ((ks*4+kg)^(row&7))*16
  int aOff[4][2], bOff[2][2];
#pragma unroll
  for (int mf = 0; mf < 4; ++mf)
#pragma unroll
    for (int ks = 0; ks < 2; ++ks) {
      const int row = wm * 64 + mf * 16 + l15;
      aOff[mf][ks] = row * 128 + (((ks * 4 + kg) ^ (row & 7)) * 16);
    }
#pragma unroll
  for (int nf = 0; nf < 2; ++nf)
#pragma unroll
    for (int ks = 0; ks < 2; ++ks) {
      const int row = wn * 32 + nf * 16 + l15;
      bOff[nf][ks] = row * 128 + (((ks * 4 + kg) ^ (row & 7)) * 16);
    }

  f32x4 acc1[4][2], acc3[4][2];
#pragma unroll
  for (int mf = 0; mf < 4; ++mf)
#pragma unroll
    for (int nf = 0; nf < 2; ++nf) {
      acc1[mf][nf] = (f32x4){0.f, 0.f, 0.f, 0.f};
      acc3[mf][nf] = (f32x4){0.f, 0.f, 0.f, 0.f};
    }

  const char* AsB = (const char*)As;
  const char* B1B = (const char*)B1s;
  const char* B3B = (const char*)B3s;

  for (int k0 = 0; k0 < HDIM; k0 += BK) {
#pragma unroll
    for (int r = 0; r < 4; ++r) gload16(aSrc[r], As + r * 2048 + wvu * 512);
#pragma unroll
    for (int r = 0; r < 2; ++r) {
      gload16(b1Src[r], B1s + r * 2048 + wvu * 512);
      gload16(b3Src[r], B3s + r * 2048 + wvu * 512);
    }
#pragma unroll
    for (int r = 0; r < 4; ++r) aSrc[r] += BK;
#pragma unroll
    for (int r = 0; r < 2; ++r) { b1Src[r] += BK; b3Src[r] += BK; }
    __syncthreads();

    short8 af[4][2], b1f[2][2], b3f[2][2];
#pragma unroll
    for (int mf = 0; mf < 4; ++mf)
#pragma unroll
      for (int ks = 0; ks < 2; ++ks)
        af[mf][ks] = *(const short8*)(AsB + aOff[mf][ks]);
#pragma unroll
    for (int nf = 0; nf < 2; ++nf)
#pragma unroll
      for (int ks = 0; ks < 2; ++ks) {
        b1f[nf][ks] = *(const short8*)(B1B + bOff[nf][ks]);
        b3f[nf][ks] = *(const short8*)(B3B + bOff[nf][ks]);
      }
#pragma unroll
    for (int mf = 0; mf < 4; ++mf)
#pragma unroll
      for (int nf = 0; nf < 2; ++nf)
#pragma unroll
        for (int ks = 0; ks < 2; ++ks) {
          acc1[mf][nf] = __builtin_amdgcn_mfma_f32_16x16x32_bf16(af[mf][ks], b1f[nf][ks], acc1[mf][nf], 0, 0, 0);
          acc3[mf][nf] = __builtin_amdgcn_mfma_f32_16x16x32_bf16(af[mf][ks], b3f[nf][ks], acc3[mf][nf], 0, 0, 0);
        }
    __syncthreads();
  }

  // epilogue: act = gelu_exact(h1) * h3 -> bf16
#pragma unroll
  for (int mf = 0; mf < 4; ++mf) {
#pragma unroll
    for (int i = 0; i < 4; ++i) {
      const int r = wm * 64 + mf * 16 + kg * 4 + i;  // C/D: row=(lane>>4)*4+i
      const int en = entry_l[r];
      if (en < 0) continue;
      unsigned short* arow = act + (size_t)en * IDIM + n0 + wn * 32;
#pragma unroll
      for (int nf = 0; nf < 2; ++nf) {
        const float h1 = acc1[mf][nf][i];
        const float h3 = acc3[mf][nf][i];
        const float g = 0.5f * h1 * (1.0f + erff(h1 * 0.70710678118f));
        arow[nf * 16 + l15] = f32_to_bf16(g * h3);  // C/D: col=lane&15
      }
    }
  }
}

// ---------------------------------------------------------------------------
// FAST GEMM2 (r5 winner): ybuf[en] = gate * (act[en] @ w2[e]^T). NO atomics.
// 256x128 tile, 512 threads (8 waves 4m x 2n), BK=64, single-buffer.
// launch_bounds(512,2): 256-VGPR budget — (512,4) forced a 128-VGPR cap and
// spilled (r7: gemm2 ~87 us vs r5's ~49 us). Keep 2 waves/EU minimum.
// ---------------------------------------------------------------------------
__global__ __launch_bounds__(512, 2)
void moe_gemm2_fast(const unsigned short* __restrict__ act,
                    const unsigned short* __restrict__ w2b,
                    const int* __restrict__ counts, const int* __restrict__ list,
                    const float* __restrict__ gate_a,
                    float* __restrict__ ybuf) {
  const int e = blockIdx.z;
  const int cnt = counts[e];
  const int m0 = blockIdx.y * 256;
  if (m0 >= cnt) return;
  const int n0 = blockIdx.x * 128;

  __shared__ __align__(16) unsigned short As[256 * BK];   // 32 KiB
  __shared__ __align__(16) unsigned short Bs[128 * BK];   // 16 KiB
  __shared__ int entry_l[256];

  const int tid = threadIdx.x;
  if (tid < 256) entry_l[tid] = (m0 + tid < cnt) ? list[e * T_TOK + m0 + tid] : -1;
  __syncthreads();

  const int lane = tid & 63;
  const int l15 = lane & 15;
  const int kg  = lane >> 4;
  const int wid = tid >> 6;
  const int wvu = __builtin_amdgcn_readfirstlane(wid);
  const int wm = wid >> 1, wn = wid & 1;

  const int srow8  = lane >> 3;
  const int schunk = (lane & 7) ^ srow8;

  const unsigned short* aSrc[4];
#pragma unroll
  for (int r = 0; r < 4; ++r) {
    const int row = r * 64 + wid * 8 + srow8;
    const int en = entry_l[row];
    const int arow = (en >= 0) ? en : 0;
    aSrc[r] = act + (size_t)arow * IDIM + schunk * 8;
  }
  const unsigned short* bSrc[2];
#pragma unroll
  for (int r = 0; r < 2; ++r) {
    const int row = r * 64 + wid * 8 + srow8;
    bSrc[r] = w2b + ((size_t)e * HDIM + n0 + row) * IDIM + schunk * 8;
  }

  int aOff[4][2], bOff[4][2];
#pragma unroll
  for (int mf = 0; mf < 4; ++mf)
#pragma unroll
    for (int ks = 0; ks < 2; ++ks) {
      const int row = wm * 64 + mf * 16 + l15;
      aOff[mf][ks] = row * 128 + (((ks * 4 + kg) ^ (row & 7)) * 16);
    }
#pragma unroll
  for (int nf = 0; nf < 4; ++nf)
#pragma unroll
    for (int ks = 0; ks < 2; ++ks) {
      const int row = wn * 64 + nf * 16 + l15;
      bOff[nf][ks] = row * 128 + (((ks * 4 + kg) ^ (row & 7)) * 16);
    }

  f32x4 acc[4][4];
#pragma unroll
  for (int mf = 0; mf < 4; ++mf)
#pragma unroll
    for (int nf = 0; nf < 4; ++nf) acc[mf][nf] = (f32x4){0.f, 0.f, 0.f, 0.f};

  const char* AsB = (const char*)As;
  const char* BsB = (const char*)Bs;

  for (int k0 = 0; k0 < IDIM; k0 += BK) {
#pragma unroll
    for (int r = 0; r < 4; ++r) gload16(aSrc[r], As + r * 4096 + wvu * 512);
#pragma unroll
    for (int r = 0; r < 2; ++r) gload16(bSrc[r], Bs + r * 4096 + wvu * 512);
#pragma unroll
    for (int r = 0; r < 4; ++r) aSrc[r] += BK;
#pragma unroll
    for (int r = 0; r < 2; ++r) bSrc[r] += BK;
    __syncthreads();

    short8 af[4][2], bf[4][2];
#pragma unroll
    for (int mf = 0; mf < 4; ++mf)
#pragma unroll
      for (int ks = 0; ks < 2; ++ks)
        af[mf][ks] = *(const short8*)(AsB + aOff[mf][ks]);
#pragma unroll
    for (int nf = 0; nf < 4; ++nf)
#pragma unroll
      for (int ks = 0; ks < 2; ++ks)
        bf[nf][ks] = *(const short8*)(BsB + bOff[nf][ks]);
#pragma unroll
    for (int mf = 0; mf < 4; ++mf)
#pragma unroll
      for (int nf = 0; nf < 4; ++nf)
#pragma unroll
        for (int ks = 0; ks < 2; ++ks)
          acc[mf][nf] = __builtin_amdgcn_mfma_f32_16x16x32_bf16(af[mf][ks], bf[nf][ks], acc[mf][nf], 0, 0, 0);
    __syncthreads();
  }

#pragma unroll
  for (int mf = 0; mf < 4; ++mf) {
#pragma unroll
    for (int i = 0; i < 4; ++i) {
      const int r = wm * 64 + mf * 16 + kg * 4 + i;
      const int en = entry_l[r];
      if (en < 0) continue;
      const float gate = gate_a[en];
      float* yrow = ybuf + (size_t)en * HDIM + n0 + wn * 64;
#pragma unroll
      for (int nf = 0; nf < 4; ++nf)
        yrow[nf * 16 + l15] = acc[mf][nf][i] * gate;
    }
  }
}

// ---------------------------------------------------------------------------
// combine: out[t] = ybuf[2t] + ybuf[2t+1]
// ---------------------------------------------------------------------------
__global__ __launch_bounds__(256)
void combine_kernel(const float* __restrict__ ybuf, float* __restrict__ out) {
  const int i = blockIdx.x * 256 + threadIdx.x;
  const int t  = i >> 8;
  const int j4 = i & 255;
  const float4 a = ((const float4*)(ybuf + (size_t)(2 * t) * HDIM))[j4];
  const float4 b = ((const float4*)(ybuf + (size_t)(2 * t + 1) * HDIM))[j4];
  float4 o;
  o.x = a.x + b.x; o.y = a.y + b.y; o.z = a.z + b.z; o.w = a.w + b.w;
  ((float4*)out)[i] = o;
}

// ---------------------------------------------------------------------------
// FALLBACK path — used only if ws_size can't hold bf16 weight copies.
// ---------------------------------------------------------------------------
#define LSTRIDE 40

__global__ __launch_bounds__(256, 2)
void moe_gemm1_fb(const unsigned short* __restrict__ xb,
                  const float* __restrict__ w1, const float* __restrict__ w3,
                  const int* __restrict__ counts, const int* __restrict__ list,
                  unsigned short* __restrict__ act) {
  const int e = blockIdx.z;
  const int cnt = counts[e];
  const int m0 = blockIdx.y * 128;
  if (m0 >= cnt) return;
  const int n0 = blockIdx.x * 64;

  __shared__ short As[128 * LSTRIDE];
  __shared__ short B1s[64 * LSTRIDE];
  __shared__ short B3s[64 * LSTRIDE];
  __shared__ int entry_l[128];

  const int tid = threadIdx.x;
  if (tid < 128) entry_l[tid] = (m0 + tid < cnt) ? list[e * T_TOK + m0 + tid] : -1;
  __syncthreads();

  const int lane = tid & 63;
  const int l15 = lane & 15;
  const int kg = lane >> 4;
  const int wv = tid >> 6;
  const int wm = wv >> 1, wn = wv & 1;

  f32x4 acc1[4][2], acc3[4][2];
#pragma unroll
  for (int mf = 0; mf < 4; ++mf)
#pragma unroll
    for (int nf = 0; nf < 2; ++nf) {
      acc1[mf][nf] = (f32x4){0.f, 0.f, 0.f, 0.f};
      acc3[mf][nf] = (f32x4){0.f, 0.f, 0.f, 0.f};
    }

  const int srow = tid >> 2;
  const int scol = (tid & 3) << 3;

  const float* w1base = w1 + ((size_t)e * IDIM + n0) * HDIM;
  const float* w3base = w3 + ((size_t)e * IDIM + n0) * HDIM;

  for (int k0 = 0; k0 < HDIM; k0 += 32) {
#pragma unroll
    for (int it = 0; it < 2; ++it) {
      const int r = srow + it * 64;
      const int en = entry_l[r];
      uint4 v = {0u, 0u, 0u, 0u};
      if (en >= 0)
        v = *(const uint4*)(xb + ((size_t)(en >> 1) * HDIM + k0 + scol));
      *(uint4*)(&As[r * LSTRIDE + scol]) = v;
    }
    {
      const float* p1 = w1base + (size_t)srow * HDIM + k0 + scol;
      float4 a0 = *(const float4*)(p1);
      float4 a1 = *(const float4*)(p1 + 4);
      short8 sb;
      sb[0] = f32_to_bf16(a0.x); sb[1] = f32_to_bf16(a0.y);
      sb[2] = f32_to_bf16(a0.z); sb[3] = f32_to_bf16(a0.w);
      sb[4] = f32_to_bf16(a1.x); sb[5] = f32_to_bf16(a1.y);
      sb[6] = f32_to_bf16(a1.z); sb[7] = f32_to_bf16(a1.w);
      *(short8*)(&B1s[srow * LSTRIDE + scol]) = sb;
      const float* p3 = w3base + (size_t)srow * HDIM + k0 + scol;
      float4 c0 = *(const float4*)(p3);
      float4 c1 = *(const float4*)(p3 + 4);
      sb[0] = f32_to_bf16(c0.x); sb[1] = f32_to_bf16(c0.y);
      sb[2] = f32_to_bf16(c0.z); sb[3] = f32_to_bf16(c0.w);
      sb[4] = f32_to_bf16(c1.x); sb[5] = f32_to_bf16(c1.y);
      sb[6] = f32_to_bf16(c1.z); sb[7] = f32_to_bf16(c1.w);
      *(short8*)(&B3s[srow * LSTRIDE + scol]) = sb;
    }
    __syncthreads();
    short8 af[4], b1f[2], b3f[2];
#pragma unroll
    for (int mf = 0; mf < 4; ++mf)
      af[mf] = *(const short8*)(&As[(wm * 64 + mf * 16 + l15) * LSTRIDE + kg * 8]);
#pragma unroll
    for (int nf = 0; nf < 2; ++nf) {
      b1f[nf] = *(const short8*)(&B1s[(wn * 32 + nf * 16 + l15) * LSTRIDE + kg * 8]);
      b3f[nf] = *(const short8*)(&B3s[(wn * 32 + nf * 16 + l15) * LSTRIDE + kg * 8]);
    }
#pragma unroll
    for (int mf = 0; mf < 4; ++mf)
#pragma unroll
      for (int nf = 0; nf < 2; ++nf) {
        acc1[mf][nf] = __builtin_amdgcn_mfma_f32_16x16x32_bf16(af[mf], b1f[nf], acc1[mf][nf], 0, 0, 0);
        acc3[mf][nf] = __builtin_amdgcn_mfma_f32_16x16x32_bf16(af[mf], b3f[nf], acc3[mf][nf], 0, 0, 0);
      }
    __syncthreads();
  }

#pragma unroll
  for (int mf = 0; mf < 4; ++mf) {
#pragma unroll
    for (int i = 0; i < 4; ++i) {
      const int r = wm * 64 + mf * 16 + kg * 4 + i;
      const int en = entry_l[r];
      if (en < 0) continue;
      unsigned short* arow = act + (size_t)en * IDIM + n0 + wn * 32;
#pragma unroll
      for (int nf = 0; nf < 2; ++nf) {
        const float h1 = acc1[mf][nf][i];
        const float h3 = acc3[mf][nf][i];
        const float g = 0.5f * h1 * (1.0f + erff(h1 * 0.70710678118f));
        arow[nf * 16 + l15] = f32_to_bf16(g * h3);
      }
    }
  }
}

__global__ __launch_bounds__(256, 2)
void moe_gemm2_fb(const unsigned short* __restrict__ act,
                  const float* __restrict__ w2,
                  const int* __restrict__ counts, const int* __restrict__ list,
                  const float* __restrict__ gate_a,
                  float* __restrict__ out) {
  const int e = blockIdx.z;
  const int cnt = counts[e];
  const int m0 = blockIdx.y * 128;
  if (m0 >= cnt) return;
  const int n0 = blockIdx.x * 64;

  __shared__ short As[128 * LSTRIDE];
  __shared__ short Bs[64 * LSTRIDE];
  __shared__ int entry_l[128];

  const int tid = threadIdx.x;
  if (tid < 128) entry_l[tid] = (m0 + tid < cnt) ? list[e * T_TOK + m0 + tid] : -1;
  __syncthreads();

  const int lane = tid & 63;
  const int l15 = lane & 15;
  const int kg = lane >> 4;
  const int wv = tid >> 6;
  const int wm = wv >> 1, wn = wv & 1;

  f32x4 acc[4][2];
#pragma unroll
  for (int mf = 0; mf < 4; ++mf)
#pragma unroll
    for (int nf = 0; nf < 2; ++nf) acc[mf][nf] = (f32x4){0.f, 0.f, 0.f, 0.f};

  const int srow = tid >> 2;
  const int scol = (tid & 3) << 3;

  const float* w2b2 = w2 + ((size_t)e * HDIM + n0) * IDIM;

  for (int k0 = 0; k0 < IDIM; k0 += 32) {
#pragma unroll
    for (int it = 0; it < 2; ++it) {
      const int r = srow + it * 64;
      const int en = entry_l[r];
      uint4 v = {0u, 0u, 0u, 0u};
      if (en >= 0)
        v = *(const uint4*)(act + ((size_t)en * IDIM + k0 + scol));
      *(uint4*)(&As[r * LSTRIDE + scol]) = v;
    }
    {
      const float* p2 = w2b2 + (size_t)srow * IDIM + k0 + scol;
      float4 a0 = *(const float4*)(p2);
      float4 a1 = *(const float4*)(p2 + 4);
      short8 sb;
      sb[0] = f32_to_bf16(a0.x); sb[1] = f32_to_bf16(a0.y);
      sb[2] = f32_to_bf16(a0.z); sb[3] = f32_to_bf16(a0.w);
      sb[4] = f32_to_bf16(a1.x); sb[5] = f32_to_bf16(a1.y);
      sb[6] = f32_to_bf16(a1.z); sb[7] = f32_to_bf16(a1.w);
      *(short8*)(&Bs[srow * LSTRIDE + scol]) = sb;
    }
    __syncthreads();
    short8 af[4], bf[2];
#pragma unroll
    for (int mf = 0; mf < 4; ++mf)
      af[mf] = *(const short8*)(&As[(wm * 64 + mf * 16 + l15) * LSTRIDE + kg * 8]);
#pragma unroll
    for (int nf = 0; nf < 2; ++nf)
      bf[nf] = *(const short8*)(&Bs[(wn * 32 + nf * 16 + l15) * LSTRIDE + kg * 8]);
#pragma unroll
    for (int mf = 0; mf < 4; ++mf)
#pragma unroll
      for (int nf = 0; nf < 2; ++nf)
        acc[mf][nf] = __builtin_amdgcn_mfma_f32_16x16x32_bf16(af[mf], bf[nf], acc[mf][nf], 0, 0, 0);
    __syncthreads();
  }

#pragma unroll
  for (int mf = 0; mf < 4; ++mf) {
#pragma unroll
    for (int i = 0; i < 4; ++i) {
      const int r = wm * 64 + mf * 16 + kg * 4 + i;
      const int en = entry_l[r];
      if (en < 0) continue;
      const float gate = gate_a[en];
      float* orow = out + (size_t)(en >> 1) * HDIM + n0 + wn * 32;
#pragma unroll
      for (int nf = 0; nf < 2; ++nf)
        atomicAdd(&orow[nf * 16 + l15], acc[mf][nf][i] * gate);
    }
  }
}

// ---------------------------------------------------------------------------
// Launch
// ---------------------------------------------------------------------------
extern "C" void kernel_launch(void* const* d_in, const int* in_sizes, int n_in,
                              void* d_out, int out_size, void* d_ws, size_t ws_size,
                              hipStream_t stream) {
  const float* x  = (const float*)d_in[0];  // [4,1024,1024]
  const float* wg = (const float*)d_in[1];  // [8,1024]
  const float* w1 = (const float*)d_in[2];  // [8,2048,1024]
  const float* w3 = (const float*)d_in[3];  // [8,2048,1024]
  const float* w2 = (const float*)d_in[4];  // [8,1024,2048]
  float* out = (float*)d_out;

  // ws layout
  char* ws = (char*)d_ws;
  int*            counts = (int*)ws;                               // 1 KiB
  int*            list   = (int*)(ws + 1024);                      // 128 KiB
  float*          gate_a = (float*)(ws + 132096);                  // 32 KiB
  unsigned char*  eids   = (unsigned char*)(ws + 165888);          // 8 KiB
  unsigned short* xb     = (unsigned short*)(ws + 262144);         // 8 MiB
  const size_t OFF_ACT = 262144 + (size_t)T_TOK * HDIM * 2;        // 8650752
  unsigned short* act    = (unsigned short*)(ws + OFF_ACT);        // 32 MiB
  const size_t WELEMS = (size_t)NEXP * IDIM * HDIM;                // 16.8M
  const size_t OFF_W1B = OFF_ACT + (size_t)2 * T_TOK * IDIM * 2;   // 42205184
  const size_t OFF_W3B = OFF_W1B + WELEMS * 2;
  const size_t OFF_W2B = OFF_W3B + WELEMS * 2;
  const size_t WS_NEED = OFF_W2B + WELEMS * 2;                     // ~136.3 MiB

  // router core (no atomics) + deterministic list build
  router_core<<<T_TOK / 8, 256, 0, stream>>>(x, wg, xb, eids, gate_a);
  build_lists<<<NEXP, 1024, 0, stream>>>(eids, counts, list);

  if (ws_size >= WS_NEED) {
    unsigned short* w1b = (unsigned short*)(ws + OFF_W1B);
    unsigned short* w3b = (unsigned short*)(ws + OFF_W3B);
    unsigned short* w2b = (unsigned short*)(ws + OFF_W2B);
    // ybuf (32 MiB f32) aliases w1b (33.5 MiB): w1b is dead once gemm1 completes.
    float* ybuf = (float*)(ws + OFF_W1B);
    const int n8 = (int)(WELEMS / 8);
    cast_w3_kernel<<<dim3((n8 + 255) / 256, 3), 256, 0, stream>>>(w1, w3, w2, w1b, w3b, w2b, n8);
    moe_gemm1_fast<<<dim3(IDIM / 64, T_TOK / 128, NEXP), 256, 0, stream>>>(xb, w1b, w3b, counts, list, act);
    moe_gemm2_fast<<<dim3(HDIM / 128, T_TOK / 256, NEXP), 512, 0, stream>>>(act, w2b, counts, list, gate_a, ybuf);
    combine_kernel<<<T_TOK * HDIM / 4 / 256, 256, 0, stream>>>(ybuf, out);
  } else {
    hipMemsetAsync(d_out, 0, (size_t)out_size * sizeof(float), stream);
    moe_gemm1_fb<<<dim3(IDIM / 64, T_TOK / 128, NEXP), 256, 0, stream>>>(xb, w1, w3, counts, list, act);
    moe_gemm2_fb<<<dim3(HDIM / 64, T_TOK / 128, NEXP), 256, 0, stream>>>(act, w2, counts, list, gate_a, out);
  }
}

// Round 9
// 212.630 us; speedup vs baseline: 1.3499x; 1.0682x over previous
//
#include <hip/hip_runtime.h>
#include <stdint.h>

// Problem constants (Grok1MoE): B=4, S=1024 -> T=4096 tokens
#define T_TOK 4096
#define HDIM  1024
#define NEXP  8
#define IDIM  2048
#define BK    64
#define NASSIGN (T_TOK * 2)
#define N8W   (NEXP * IDIM * HDIM / 8)   // short8 chunks per weight tensor = 2097152
#define CASTBLK (N8W / 256)              // 8192 blocks per tensor cast

typedef short short8 __attribute__((ext_vector_type(8)));
typedef float f32x4 __attribute__((ext_vector_type(4)));

__device__ __forceinline__ unsigned short f32_to_bf16(float f) {
  union { float f; uint32_t u; } v; v.f = f;
  uint32_t r = 0x7FFFu + ((v.u >> 16) & 1u);   // round-to-nearest-even
  return (unsigned short)((v.u + r) >> 16);
}

__device__ __forceinline__ void gload16(const void* g, void* l) {
  __builtin_amdgcn_global_load_lds(
      (const __attribute__((address_space(1))) uint32_t*)g,
      (__attribute__((address_space(3))) uint32_t*)l, 16, 0, 0);
}

__device__ __forceinline__ void cast8(const float* __restrict__ src,
                                      unsigned short* __restrict__ dst, int i) {
  const float4* s = (const float4*)src + (size_t)i * 2;
  float4 a = s[0], b = s[1];
  short8 o;
  o[0] = f32_to_bf16(a.x); o[1] = f32_to_bf16(a.y);
  o[2] = f32_to_bf16(a.z); o[3] = f32_to_bf16(a.w);
  o[4] = f32_to_bf16(b.x); o[5] = f32_to_bf16(b.y);
  o[6] = f32_to_bf16(b.z); o[7] = f32_to_bf16(b.w);
  ((short8*)dst)[i] = o;
}

// ---------------------------------------------------------------------------
// PREP: router + x-cast (blocks 0..511)  ||  w1,w3 f32->bf16 cast (rest).
// Router hides under the w1/w3 cast's HBM streaming.
// ---------------------------------------------------------------------------
__global__ __launch_bounds__(256)
void prep_kernel(const float* __restrict__ x, const float* __restrict__ wg,
                 unsigned short* __restrict__ xb,
                 unsigned char* __restrict__ eids,
                 float* __restrict__ gate_a,
                 const float* __restrict__ w1, const float* __restrict__ w3,
                 unsigned short* __restrict__ w1b, unsigned short* __restrict__ w3b) {
  const int bid = blockIdx.x;
  const int tid = threadIdx.x;

  if (bid >= 512) {                       // ---- cast path (w1 then w3)
    const int cb = bid - 512;
    const int i = (cb & (CASTBLK - 1)) * 256 + tid;
    if (cb < CASTBLK) cast8(w1, w1b, i);
    else              cast8(w3, w3b, i);
    return;
  }

  // ---- router path (identical math to the proven router_core)
  __shared__ float wgs[NEXP * HDIM];   // 32 KiB
#pragma unroll
  for (int i = 0; i < NEXP * HDIM / 4 / 256; ++i)
    ((float4*)wgs)[i * 256 + tid] = ((const float4*)wg)[i * 256 + tid];
  __syncthreads();

  const int wv = tid >> 6, lane = tid & 63;
#pragma unroll
  for (int tt = 0; tt < 2; ++tt) {
    const int t = bid * 8 + wv * 2 + tt;
    const float* xr = x + (size_t)t * HDIM;
    float acc0 = 0.f, acc1v = 0.f, acc2 = 0.f, acc3 = 0.f;
    float acc4 = 0.f, acc5 = 0.f, acc6 = 0.f, acc7 = 0.f;
#pragma unroll
    for (int it = 0; it < 4; ++it) {
      const int j = it * 256 + lane * 4;
      const float4 xv = *(const float4*)(xr + j);
      ushort4 u;
      u.x = f32_to_bf16(xv.x); u.y = f32_to_bf16(xv.y);
      u.z = f32_to_bf16(xv.z); u.w = f32_to_bf16(xv.w);
      *(ushort4*)(xb + (size_t)t * HDIM + j) = u;
      const float4 g0 = *(const float4*)(wgs + 0 * HDIM + j);
      const float4 g1 = *(const float4*)(wgs + 1 * HDIM + j);
      const float4 g2 = *(const float4*)(wgs + 2 * HDIM + j);
      const float4 g3 = *(const float4*)(wgs + 3 * HDIM + j);
      const float4 g4 = *(const float4*)(wgs + 4 * HDIM + j);
      const float4 g5 = *(const float4*)(wgs + 5 * HDIM + j);
      const float4 g6 = *(const float4*)(wgs + 6 * HDIM + j);
      const float4 g7 = *(const float4*)(wgs + 7 * HDIM + j);
      acc0 += xv.x * g0.x + xv.y * g0.y + xv.z * g0.z + xv.w * g0.w;
      acc1v += xv.x * g1.x + xv.y * g1.y + xv.z * g1.z + xv.w * g1.w;
      acc2 += xv.x * g2.x + xv.y * g2.y + xv.z * g2.z + xv.w * g2.w;
      acc3 += xv.x * g3.x + xv.y * g3.y + xv.z * g3.z + xv.w * g3.w;
      acc4 += xv.x * g4.x + xv.y * g4.y + xv.z * g4.z + xv.w * g4.w;
      acc5 += xv.x * g5.x + xv.y * g5.y + xv.z * g5.z + xv.w * g5.w;
      acc6 += xv.x * g6.x + xv.y * g6.y + xv.z * g6.z + xv.w * g6.w;
      acc7 += xv.x * g7.x + xv.y * g7.y + xv.z * g7.z + xv.w * g7.w;
    }
    float acc[NEXP] = {acc0, acc1v, acc2, acc3, acc4, acc5, acc6, acc7};
#pragma unroll
    for (int e = 0; e < NEXP; ++e) {
#pragma unroll
      for (int off = 32; off > 0; off >>= 1) acc[e] += __shfl_xor(acc[e], off);
    }
    if (lane == 0) {
      float p[NEXP];
      float mx = -1e30f;
#pragma unroll
      for (int e = 0; e < NEXP; ++e) {
        float l = 30.0f * tanhf(acc[e] * (1.0f / 30.0f));
        p[e] = l;
        mx = fmaxf(mx, l);
      }
      float s = 0.f;
#pragma unroll
      for (int e = 0; e < NEXP; ++e) { p[e] = expf(p[e] - mx); s += p[e]; }
      const float inv = 1.0f / s;
#pragma unroll
      for (int e = 0; e < NEXP; ++e) p[e] *= inv;
      int i0 = 0;
#pragma unroll
      for (int e = 1; e < NEXP; ++e) if (p[e] > p[i0]) i0 = e;
      int i1 = (i0 == 0) ? 1 : 0;
#pragma unroll
      for (int e = 0; e < NEXP; ++e) if (e != i1 && e != i0 && p[e] > p[i1]) i1 = e;
      eids[t * 2]     = (unsigned char)i0;
      gate_a[t * 2]   = p[i0];
      eids[t * 2 + 1] = (unsigned char)i1;
      gate_a[t * 2 + 1] = p[i1];
    }
  }
}

// ---------------------------------------------------------------------------
// Build per-expert compacted lists with ballot prefix sums. 8 blocks x 1024.
// ---------------------------------------------------------------------------
__global__ __launch_bounds__(1024)
void build_lists(const unsigned char* __restrict__ eids,
                 int* __restrict__ counts, int* __restrict__ list) {
  const int e = blockIdx.x;
  const int tid = threadIdx.x;
  const int wid = tid >> 6, lane = tid & 63;
  __shared__ int wave_tot[16];
  __shared__ int running;
  if (tid == 0) running = 0;
  __syncthreads();
#pragma unroll
  for (int c = 0; c < NASSIGN; c += 1024) {
    const int slot = c + tid;
    const bool match = ((int)eids[slot] == e);
    const unsigned long long mask = __ballot(match);
    if (lane == 0) wave_tot[wid] = __popcll(mask);
    __syncthreads();
    int base = running;
    for (int w = 0; w < wid; ++w) base += wave_tot[w];
    if (match) {
      const int pre = __popcll(mask & ((1ull << lane) - 1ull));
      list[e * T_TOK + base + pre] = slot;
    }
    __syncthreads();
    if (tid == 0) {
      int tot = 0;
      for (int w = 0; w < 16; ++w) tot += wave_tot[w];
      running += tot;
    }
    __syncthreads();
  }
  if (tid == 0) counts[e] = running;
}

// ---------------------------------------------------------------------------
// GEMM1 (r4 winner, flattened grid) || w2 cast (blocks >= 8192).
// gemm1: 128x(64+64) tile, 256 threads, BK=64, single-buffer,
// global_load_lds + XOR-chunk swizzle. w2 cast hides under gemm1 compute.
// ---------------------------------------------------------------------------
__global__ __launch_bounds__(256, 4)
void gemm1_castw2(const unsigned short* __restrict__ xb,
                  const unsigned short* __restrict__ w1b,
                  const unsigned short* __restrict__ w3b,
                  const int* __restrict__ counts, const int* __restrict__ list,
                  unsigned short* __restrict__ act,
                  const float* __restrict__ w2, unsigned short* __restrict__ w2b) {
  const int bid = blockIdx.x;
  const int tid = threadIdx.x;

  if (bid >= 8192) {                      // ---- w2 cast path
    const int i = (bid - 8192) * 256 + tid;
    cast8(w2, w2b, i);
    return;
  }

  // ---- gemm1 path: decode n/m/e from flattened bid (was dim3(32,32,8))
  const int e  = bid >> 10;
  const int m0 = ((bid >> 5) & 31) * 128;
  const int n0 = (bid & 31) * 64;
  const int cnt = counts[e];
  if (m0 >= cnt) return;

  __shared__ __align__(16) unsigned short As[128 * BK];   // 16 KiB
  __shared__ __align__(16) unsigned short B1s[64 * BK];   // 8 KiB
  __shared__ __align__(16) unsigned short B3s[64 * BK];   // 8 KiB
  __shared__ int entry_l[128];

  if (tid < 128) entry_l[tid] = (m0 + tid < cnt) ? list[e * T_TOK + m0 + tid] : -1;
  __syncthreads();

  const int lane = tid & 63;
  const int l15 = lane & 15;
  const int kg  = lane >> 4;
  const int wv  = tid >> 6;
  const int wvu = __builtin_amdgcn_readfirstlane(wv);
  const int wm = wv >> 1, wn = wv & 1;

  const int srow8  = lane >> 3;              // row & 7
  const int schunk = (lane & 7) ^ srow8;     // inverse-swizzled source chunk

  const unsigned short* aSrc[4];
#pragma unroll
  for (int r = 0; r < 4; ++r) {
    const int row = r * 32 + wv * 8 + srow8;
    const int en = entry_l[row];
    const int tok = (en >= 0) ? (en >> 1) : 0;
    aSrc[r] = xb + (size_t)tok * HDIM + schunk * 8;
  }
  const unsigned short* b1Src[2];
  const unsigned short* b3Src[2];
#pragma unroll
  for (int r = 0; r < 2; ++r) {
    const int row = r * 32 + wv * 8 + srow8;
    b1Src[r] = w1b + ((size_t)e * IDIM + n0 + row) * HDIM + schunk * 8;
    b3Src[r] = w3b + ((size_t)e * IDIM + n0 + row) * HDIM + schunk * 8;
  }

  // ds_read byte offsets: byte = row*128 + ((ks*4+kg)^(row&7))*16
  int aOff[4][2], bOff[2][2];
#pragma unroll
  for (int mf = 0; mf < 4; ++mf)
#pragma unroll
    for (int ks = 0; ks < 2; ++ks) {
      const int row = wm * 64 + mf * 16 + l15;
      aOff[mf][ks] = row * 128 + (((ks * 4 + kg) ^ (row & 7)) * 16);
    }
#pragma unroll
  for (int nf = 0; nf < 2; ++nf)
#pragma unroll
    for (int ks = 0; ks < 2; ++ks) {
      const int row = wn * 32 + nf * 16 + l15;
      bOff[nf][ks] = row * 128 + (((ks * 4 + kg) ^ (row & 7)) * 16);
    }

  f32x4 acc1[4][2], acc3[4][2];
#pragma unroll
  for (int mf = 0; mf < 4; ++mf)
#pragma unroll
    for (int nf = 0; nf < 2; ++nf) {
      acc1[mf][nf] = (f32x4){0.f, 0.f, 0.f, 0.f};
      acc3[mf][nf] = (f32x4){0.f, 0.f, 0.f, 0.f};
    }

  const char* AsB = (const char*)As;
  const char* B1B = (const char*)B1s;
  const char* B3B = (const char*)B3s;

  for (int k0 = 0; k0 < HDIM; k0 += BK) {
#pragma unroll
    for (int r = 0; r < 4; ++r) gload16(aSrc[r], As + r * 2048 + wvu * 512);
#pragma unroll
    for (int r = 0; r < 2; ++r) {
      gload16(b1Src[r], B1s + r * 2048 + wvu * 512);
      gload16(b3Src[r], B3s + r * 2048 + wvu * 512);
    }
#pragma unroll
    for (int r = 0; r < 4; ++r) aSrc[r] += BK;
#pragma unroll
    for (int r = 0; r < 2; ++r) { b1Src[r] += BK; b3Src[r] += BK; }
    __syncthreads();

    short8 af[4][2], b1f[2][2], b3f[2][2];
#pragma unroll
    for (int mf = 0; mf < 4; ++mf)
#pragma unroll
      for (int ks = 0; ks < 2; ++ks)
        af[mf][ks] = *(const short8*)(AsB + aOff[mf][ks]);
#pragma unroll
    for (int nf = 0; nf < 2; ++nf)
#pragma unroll
      for (int ks = 0; ks < 2; ++ks) {
        b1f[nf][ks] = *(const short8*)(B1B + bOff[nf][ks]);
        b3f[nf][ks] = *(const short8*)(B3B + bOff[nf][ks]);
      }
#pragma unroll
    for (int mf = 0; mf < 4; ++mf)
#pragma unroll
      for (int nf = 0; nf < 2; ++nf)
#pragma unroll
        for (int ks = 0; ks < 2; ++ks) {
          acc1[mf][nf] = __builtin_amdgcn_mfma_f32_16x16x32_bf16(af[mf][ks], b1f[nf][ks], acc1[mf][nf], 0, 0, 0);
          acc3[mf][nf] = __builtin_amdgcn_mfma_f32_16x16x32_bf16(af[mf][ks], b3f[nf][ks], acc3[mf][nf], 0, 0, 0);
        }
    __syncthreads();
  }

  // epilogue: act = gelu_exact(h1) * h3 -> bf16
#pragma unroll
  for (int mf = 0; mf < 4; ++mf) {
#pragma unroll
    for (int i = 0; i < 4; ++i) {
      const int r = wm * 64 + mf * 16 + kg * 4 + i;  // C/D: row=(lane>>4)*4+i
      const int en = entry_l[r];
      if (en < 0) continue;
      unsigned short* arow = act + (size_t)en * IDIM + n0 + wn * 32;
#pragma unroll
      for (int nf = 0; nf < 2; ++nf) {
        const float h1 = acc1[mf][nf][i];
        const float h3 = acc3[mf][nf][i];
        const float g = 0.5f * h1 * (1.0f + erff(h1 * 0.70710678118f));
        arow[nf * 16 + l15] = f32_to_bf16(g * h3);  // C/D: col=lane&15
      }
    }
  }
}

// ---------------------------------------------------------------------------
// GEMM2 (r5 winner): ybuf[en] = gate * (act[en] @ w2[e]^T). NO atomics.
// 256x128 tile, 512 threads (8 waves 4m x 2n), BK=64, single-buffer.
// launch_bounds(512,2): (512,4) caps VGPR at 128 and spills (r7 lesson).
// ---------------------------------------------------------------------------
__global__ __launch_bounds__(512, 2)
void moe_gemm2_fast(const unsigned short* __restrict__ act,
                    const unsigned short* __restrict__ w2b,
                    const int* __restrict__ counts, const int* __restrict__ list,
                    const float* __restrict__ gate_a,
                    float* __restrict__ ybuf) {
  const int e = blockIdx.z;
  const int cnt = counts[e];
  const int m0 = blockIdx.y * 256;
  if (m0 >= cnt) return;
  const int n0 = blockIdx.x * 128;

  __shared__ __align__(16) unsigned short As[256 * BK];   // 32 KiB
  __shared__ __align__(16) unsigned short Bs[128 * BK];   // 16 KiB
  __shared__ int entry_l[256];

  const int tid = threadIdx.x;
  if (tid < 256) entry_l[tid] = (m0 + tid < cnt) ? list[e * T_TOK + m0 + tid] : -1;
  __syncthreads();

  const int lane = tid & 63;
  const int l15 = lane & 15;
  const int kg  = lane >> 4;
  const int wid = tid >> 6;
  const int wvu = __builtin_amdgcn_readfirstlane(wid);
  const int wm = wid >> 1, wn = wid & 1;

  const int srow8  = lane >> 3;
  const int schunk = (lane & 7) ^ srow8;

  const unsigned short* aSrc[4];
#pragma unroll
  for (int r = 0; r < 4; ++r) {
    const int row = r * 64 + wid * 8 + srow8;
    const int en = entry_l[row];
    const int arow = (en >= 0) ? en : 0;
    aSrc[r] = act + (size_t)arow * IDIM + schunk * 8;
  }
  const unsigned short* bSrc[2];
#pragma unroll
  for (int r = 0; r < 2; ++r) {
    const int row = r * 64 + wid * 8 + srow8;
    bSrc[r] = w2b + ((size_t)e * HDIM + n0 + row) * IDIM + schunk * 8;
  }

  int aOff[4][2], bOff[4][2];
#pragma unroll
  for (int mf = 0; mf < 4; ++mf)
#pragma unroll
    for (int ks = 0; ks < 2; ++ks) {
      const int row = wm * 64 + mf * 16 + l15;
      aOff[mf][ks] = row * 128 + (((ks * 4 + kg) ^ (row & 7)) * 16);
    }
#pragma unroll
  for (int nf = 0; nf < 4; ++nf)
#pragma unroll
    for (int ks = 0; ks < 2; ++ks) {
      const int row = wn * 64 + nf * 16 + l15;
      bOff[nf][ks] = row * 128 + (((ks * 4 + kg) ^ (row & 7)) * 16);
    }

  f32x4 acc[4][4];
#pragma unroll
  for (int mf = 0; mf < 4; ++mf)
#pragma unroll
    for (int nf = 0; nf < 4; ++nf) acc[mf][nf] = (f32x4){0.f, 0.f, 0.f, 0.f};

  const char* AsB = (const char*)As;
  const char* BsB = (const char*)Bs;

  for (int k0 = 0; k0 < IDIM; k0 += BK) {
#pragma unroll
    for (int r = 0; r < 4; ++r) gload16(aSrc[r], As + r * 4096 + wvu * 512);
#pragma unroll
    for (int r = 0; r < 2; ++r) gload16(bSrc[r], Bs + r * 4096 + wvu * 512);
#pragma unroll
    for (int r = 0; r < 4; ++r) aSrc[r] += BK;
#pragma unroll
    for (int r = 0; r < 2; ++r) bSrc[r] += BK;
    __syncthreads();

    short8 af[4][2], bf[4][2];
#pragma unroll
    for (int mf = 0; mf < 4; ++mf)
#pragma unroll
      for (int ks = 0; ks < 2; ++ks)
        af[mf][ks] = *(const short8*)(AsB + aOff[mf][ks]);
#pragma unroll
    for (int nf = 0; nf < 4; ++nf)
#pragma unroll
      for (int ks = 0; ks < 2; ++ks)
        bf[nf][ks] = *(const short8*)(BsB + bOff[nf][ks]);
#pragma unroll
    for (int mf = 0; mf < 4; ++mf)
#pragma unroll
      for (int nf = 0; nf < 4; ++nf)
#pragma unroll
        for (int ks = 0; ks < 2; ++ks)
          acc[mf][nf] = __builtin_amdgcn_mfma_f32_16x16x32_bf16(af[mf][ks], bf[nf][ks], acc[mf][nf], 0, 0, 0);
    __syncthreads();
  }

#pragma unroll
  for (int mf = 0; mf < 4; ++mf) {
#pragma unroll
    for (int i = 0; i < 4; ++i) {
      const int r = wm * 64 + mf * 16 + kg * 4 + i;
      const int en = entry_l[r];
      if (en < 0) continue;
      const float gate = gate_a[en];
      float* yrow = ybuf + (size_t)en * HDIM + n0 + wn * 64;
#pragma unroll
      for (int nf = 0; nf < 4; ++nf)
        yrow[nf * 16 + l15] = acc[mf][nf][i] * gate;
    }
  }
}

// ---------------------------------------------------------------------------
// combine: out[t] = ybuf[2t] + ybuf[2t+1]
// ---------------------------------------------------------------------------
__global__ __launch_bounds__(256)
void combine_kernel(const float* __restrict__ ybuf, float* __restrict__ out) {
  const int i = blockIdx.x * 256 + threadIdx.x;
  const int t  = i >> 8;
  const int j4 = i & 255;
  const float4 a = ((const float4*)(ybuf + (size_t)(2 * t) * HDIM))[j4];
  const float4 b = ((const float4*)(ybuf + (size_t)(2 * t + 1) * HDIM))[j4];
  float4 o;
  o.x = a.x + b.x; o.y = a.y + b.y; o.z = a.z + b.z; o.w = a.w + b.w;
  ((float4*)out)[i] = o;
}

// ---------------------------------------------------------------------------
// FALLBACK path — used only if ws_size can't hold bf16 weight copies.
// ---------------------------------------------------------------------------
#define LSTRIDE 40

__global__ __launch_bounds__(256, 2)
void moe_gemm1_fb(const unsigned short* __restrict__ xb,
                  const float* __restrict__ w1, const float* __restrict__ w3,
                  const int* __restrict__ counts, const int* __restrict__ list,
                  unsigned short* __restrict__ act) {
  const int e = blockIdx.z;
  const int cnt = counts[e];
  const int m0 = blockIdx.y * 128;
  if (m0 >= cnt) return;
  const int n0 = blockIdx.x * 64;

  __shared__ short As[128 * LSTRIDE];
  __shared__ short B1s[64 * LSTRIDE];
  __shared__ short B3s[64 * LSTRIDE];
  __shared__ int entry_l[128];

  const int tid = threadIdx.x;
  if (tid < 128) entry_l[tid] = (m0 + tid < cnt) ? list[e * T_TOK + m0 + tid] : -1;
  __syncthreads();

  const int lane = tid & 63;
  const int l15 = lane & 15;
  const int kg = lane >> 4;
  const int wv = tid >> 6;
  const int wm = wv >> 1, wn = wv & 1;

  f32x4 acc1[4][2], acc3[4][2];
#pragma unroll
  for (int mf = 0; mf < 4; ++mf)
#pragma unroll
    for (int nf = 0; nf < 2; ++nf) {
      acc1[mf][nf] = (f32x4){0.f, 0.f, 0.f, 0.f};
      acc3[mf][nf] = (f32x4){0.f, 0.f, 0.f, 0.f};
    }

  const int srow = tid >> 2;
  const int scol = (tid & 3) << 3;

  const float* w1base = w1 + ((size_t)e * IDIM + n0) * HDIM;
  const float* w3base = w3 + ((size_t)e * IDIM + n0) * HDIM;

  for (int k0 = 0; k0 < HDIM; k0 += 32) {
#pragma unroll
    for (int it = 0; it < 2; ++it) {
      const int r = srow + it * 64;
      const int en = entry_l[r];
      uint4 v = {0u, 0u, 0u, 0u};
      if (en >= 0)
        v = *(const uint4*)(xb + ((size_t)(en >> 1) * HDIM + k0 + scol));
      *(uint4*)(&As[r * LSTRIDE + scol]) = v;
    }
    {
      const float* p1 = w1base + (size_t)srow * HDIM + k0 + scol;
      float4 a0 = *(const float4*)(p1);
      float4 a1 = *(const float4*)(p1 + 4);
      short8 sb;
      sb[0] = f32_to_bf16(a0.x); sb[1] = f32_to_bf16(a0.y);
      sb[2] = f32_to_bf16(a0.z); sb[3] = f32_to_bf16(a0.w);
      sb[4] = f32_to_bf16(a1.x); sb[5] = f32_to_bf16(a1.y);
      sb[6] = f32_to_bf16(a1.z); sb[7] = f32_to_bf16(a1.w);
      *(short8*)(&B1s[srow * LSTRIDE + scol]) = sb;
      const float* p3 = w3base + (size_t)srow * HDIM + k0 + scol;
      float4 c0 = *(const float4*)(p3);
      float4 c1 = *(const float4*)(p3 + 4);
      sb[0] = f32_to_bf16(c0.x); sb[1] = f32_to_bf16(c0.y);
      sb[2] = f32_to_bf16(c0.z); sb[3] = f32_to_bf16(c0.w);
      sb[4] = f32_to_bf16(c1.x); sb[5] = f32_to_bf16(c1.y);
      sb[6] = f32_to_bf16(c1.z); sb[7] = f32_to_bf16(c1.w);
      *(short8*)(&B3s[srow * LSTRIDE + scol]) = sb;
    }
    __syncthreads();
    short8 af[4], b1f[2], b3f[2];
#pragma unroll
    for (int mf = 0; mf < 4; ++mf)
      af[mf] = *(const short8*)(&As[(wm * 64 + mf * 16 + l15) * LSTRIDE + kg * 8]);
#pragma unroll
    for (int nf = 0; nf < 2; ++nf) {
      b1f[nf] = *(const short8*)(&B1s[(wn * 32 + nf * 16 + l15) * LSTRIDE + kg * 8]);
      b3f[nf] = *(const short8*)(&B3s[(wn * 32 + nf * 16 + l15) * LSTRIDE + kg * 8]);
    }
#pragma unroll
    for (int mf = 0; mf < 4; ++mf)
#pragma unroll
      for (int nf = 0; nf < 2; ++nf) {
        acc1[mf][nf] = __builtin_amdgcn_mfma_f32_16x16x32_bf16(af[mf], b1f[nf], acc1[mf][nf], 0, 0, 0);
        acc3[mf][nf] = __builtin_amdgcn_mfma_f32_16x16x32_bf16(af[mf], b3f[nf], acc3[mf][nf], 0, 0, 0);
      }
    __syncthreads();
  }

#pragma unroll
  for (int mf = 0; mf < 4; ++mf) {
#pragma unroll
    for (int i = 0; i < 4; ++i) {
      const int r = wm * 64 + mf * 16 + kg * 4 + i;
      const int en = entry_l[r];
      if (en < 0) continue;
      unsigned short* arow = act + (size_t)en * IDIM + n0 + wn * 32;
#pragma unroll
      for (int nf = 0; nf < 2; ++nf) {
        const float h1 = acc1[mf][nf][i];
        const float h3 = acc3[mf][nf][i];
        const float g = 0.5f * h1 * (1.0f + erff(h1 * 0.70710678118f));
        arow[nf * 16 + l15] = f32_to_bf16(g * h3);
      }
    }
  }
}

__global__ __launch_bounds__(256, 2)
void moe_gemm2_fb(const unsigned short* __restrict__ act,
                  const float* __restrict__ w2,
                  const int* __restrict__ counts, const int* __restrict__ list,
                  const float* __restrict__ gate_a,
                  float* __restrict__ out) {
  const int e = blockIdx.z;
  const int cnt = counts[e];
  const int m0 = blockIdx.y * 128;
  if (m0 >= cnt) return;
  const int n0 = blockIdx.x * 64;

  __shared__ short As[128 * LSTRIDE];
  __shared__ short Bs[64 * LSTRIDE];
  __shared__ int entry_l[128];

  const int tid = threadIdx.x;
  if (tid < 128) entry_l[tid] = (m0 + tid < cnt) ? list[e * T_TOK + m0 + tid] : -1;
  __syncthreads();

  const int lane = tid & 63;
  const int l15 = lane & 15;
  const int kg = lane >> 4;
  const int wv = tid >> 6;
  const int wm = wv >> 1, wn = wv & 1;

  f32x4 acc[4][2];
#pragma unroll
  for (int mf = 0; mf < 4; ++mf)
#pragma unroll
    for (int nf = 0; nf < 2; ++nf) acc[mf][nf] = (f32x4){0.f, 0.f, 0.f, 0.f};

  const int srow = tid >> 2;
  const int scol = (tid & 3) << 3;

  const float* w2b2 = w2 + ((size_t)e * HDIM + n0) * IDIM;

  for (int k0 = 0; k0 < IDIM; k0 += 32) {
#pragma unroll
    for (int it = 0; it < 2; ++it) {
      const int r = srow + it * 64;
      const int en = entry_l[r];
      uint4 v = {0u, 0u, 0u, 0u};
      if (en >= 0)
        v = *(const uint4*)(act + ((size_t)en * IDIM + k0 + scol));
      *(uint4*)(&As[r * LSTRIDE + scol]) = v;
    }
    {
      const float* p2 = w2b2 + (size_t)srow * IDIM + k0 + scol;
      float4 a0 = *(const float4*)(p2);
      float4 a1 = *(const float4*)(p2 + 4);
      short8 sb;
      sb[0] = f32_to_bf16(a0.x); sb[1] = f32_to_bf16(a0.y);
      sb[2] = f32_to_bf16(a0.z); sb[3] = f32_to_bf16(a0.w);
      sb[4] = f32_to_bf16(a1.x); sb[5] = f32_to_bf16(a1.y);
      sb[6] = f32_to_bf16(a1.z); sb[7] = f32_to_bf16(a1.w);
      *(short8*)(&Bs[srow * LSTRIDE + scol]) = sb;
    }
    __syncthreads();
    short8 af[4], bf[2];
#pragma unroll
    for (int mf = 0; mf < 4; ++mf)
      af[mf] = *(const short8*)(&As[(wm * 64 + mf * 16 + l15) * LSTRIDE + kg * 8]);
#pragma unroll
    for (int nf = 0; nf < 2; ++nf)
      bf[nf] = *(const short8*)(&Bs[(wn * 32 + nf * 16 + l15) * LSTRIDE + kg * 8]);
#pragma unroll
    for (int mf = 0; mf < 4; ++mf)
#pragma unroll
      for (int nf = 0; nf < 2; ++nf)
        acc[mf][nf] = __builtin_amdgcn_mfma_f32_16x16x32_bf16(af[mf], bf[nf], acc[mf][nf], 0, 0, 0);
    __syncthreads();
  }

#pragma unroll
  for (int mf = 0; mf < 4; ++mf) {
#pragma unroll
    for (int i = 0; i < 4; ++i) {
      const int r = wm * 64 + mf * 16 + kg * 4 + i;
      const int en = entry_l[r];
      if (en < 0) continue;
      const float gate = gate_a[en];
      float* orow = out + (size_t)(en >> 1) * HDIM + n0 + wn * 32;
#pragma unroll
      for (int nf = 0; nf < 2; ++nf)
        atomicAdd(&orow[nf * 16 + l15], acc[mf][nf][i] * gate);
    }
  }
}

// ---------------------------------------------------------------------------
// Launch
// ---------------------------------------------------------------------------
extern "C" void kernel_launch(void* const* d_in, const int* in_sizes, int n_in,
                              void* d_out, int out_size, void* d_ws, size_t ws_size,
                              hipStream_t stream) {
  const float* x  = (const float*)d_in[0];  // [4,1024,1024]
  const float* wg = (const float*)d_in[1];  // [8,1024]
  const float* w1 = (const float*)d_in[2];  // [8,2048,1024]
  const float* w3 = (const float*)d_in[3];  // [8,2048,1024]
  const float* w2 = (const float*)d_in[4];  // [8,1024,2048]
  float* out = (float*)d_out;

  // ws layout
  char* ws = (char*)d_ws;
  int*            counts = (int*)ws;                               // 1 KiB
  int*            list   = (int*)(ws + 1024);                      // 128 KiB
  float*          gate_a = (float*)(ws + 132096);                  // 32 KiB
  unsigned char*  eids   = (unsigned char*)(ws + 165888);          // 8 KiB
  unsigned short* xb     = (unsigned short*)(ws + 262144);         // 8 MiB
  const size_t OFF_ACT = 262144 + (size_t)T_TOK * HDIM * 2;        // 8650752
  unsigned short* act    = (unsigned short*)(ws + OFF_ACT);        // 32 MiB
  const size_t WELEMS = (size_t)NEXP * IDIM * HDIM;                // 16.8M
  const size_t OFF_W1B = OFF_ACT + (size_t)2 * T_TOK * IDIM * 2;   // 42205184
  const size_t OFF_W3B = OFF_W1B + WELEMS * 2;
  const size_t OFF_W2B = OFF_W3B + WELEMS * 2;
  const size_t WS_NEED = OFF_W2B + WELEMS * 2;                     // ~136.3 MiB

  if (ws_size >= WS_NEED) {
    unsigned short* w1b = (unsigned short*)(ws + OFF_W1B);
    unsigned short* w3b = (unsigned short*)(ws + OFF_W3B);
    unsigned short* w2b = (unsigned short*)(ws + OFF_W2B);
    // ybuf (32 MiB f32) aliases w1b (33.5 MiB): w1b is dead once gemm1 completes.
    float* ybuf = (float*)(ws + OFF_W1B);

    // prep: router (512 blocks) || cast w1,w3 (2*8192 blocks)
    prep_kernel<<<512 + 2 * CASTBLK, 256, 0, stream>>>(x, wg, xb, eids, gate_a,
                                                       w1, w3, w1b, w3b);
    build_lists<<<NEXP, 1024, 0, stream>>>(eids, counts, list);
    // gemm1 (8192 flattened blocks) || cast w2 (8192 blocks)
    gemm1_castw2<<<8192 + CASTBLK, 256, 0, stream>>>(xb, w1b, w3b, counts, list,
                                                     act, w2, w2b);
    moe_gemm2_fast<<<dim3(HDIM / 128, T_TOK / 256, NEXP), 512, 0, stream>>>(act, w2b, counts, list, gate_a, ybuf);
    combine_kernel<<<T_TOK * HDIM / 4 / 256, 256, 0, stream>>>(ybuf, out);
  } else {
    // fallback: standalone router + f32-weight GEMMs with atomic epilogue
    prep_kernel<<<512, 256, 0, stream>>>(x, wg, xb, eids, gate_a, w1, w3,
                                         (unsigned short*)xb, (unsigned short*)xb);  // cast part unused (grid=512)
    build_lists<<<NEXP, 1024, 0, stream>>>(eids, counts, list);
    hipMemsetAsync(d_out, 0, (size_t)out_size * sizeof(float), stream);
    moe_gemm1_fb<<<dim3(IDIM / 64, T_TOK / 128, NEXP), 256, 0, stream>>>(xb, w1, w3, counts, list, act);
    moe_gemm2_fb<<<dim3(HDIM / 64, T_TOK / 128, NEXP), 256, 0, stream>>>(act, w2, counts, list, gate_a, out);
  }
}